// Round 2
// baseline (1436.802 us; speedup 1.0000x reference)
//
#include <hip/hip_runtime.h>
#include <hip/hip_bf16.h>

// LocalMamba2D: B=8, C=256, H=W=48, win=8 -> 288 windows x 64 tokens.
// D_INNER=512, DSTATE=16, DT_RANK=16, DCONV=4.
// Inputs/outputs fp32 (reference dtype). bf16 only for LDS weight tiles.

typedef unsigned short u16;
typedef __attribute__((ext_vector_type(8))) unsigned short u16x8;
typedef __attribute__((ext_vector_type(4))) unsigned short u16x4;
typedef __attribute__((ext_vector_type(4))) float f32x4;

#define NTOK 18432      // 288 windows * 64 tokens
#define NWIN 288

__device__ __forceinline__ float bu2f(u16 u) {
    union { unsigned int i; float f; } v; v.i = ((unsigned int)u) << 16; return v.f;
}
__device__ __forceinline__ u16 f2bu(float f) {
    union { float f; unsigned int i; } v; v.f = f;
    unsigned int i = v.i;
    unsigned int r = (i + 0x7FFFu + ((i >> 16) & 1u)) >> 16;
    return (u16)r;
}
__device__ __forceinline__ float silu(float v) {
    return v * (1.f / (1.f + __expf(-v)));
}

// ---------------------------------------------------------------------------
// K1: proj_in (1x1 conv over C) + window partition + LayerNorm -> t (NTOK,256) f32
// grid NTOK, block 128 (each thread computes 2 output channels)
// ---------------------------------------------------------------------------
__global__ __launch_bounds__(128) void k1_proj_ln(
    const float* __restrict__ x, const float* __restrict__ pw, const float* __restrict__ pb,
    const float* __restrict__ lg, const float* __restrict__ lb, float* __restrict__ t) {
    int tok = blockIdx.x, tid = threadIdx.x;
    int wi = tok >> 6, l = tok & 63;
    int b = wi / 36; int rem = wi - b * 36; int ih = rem / 6; int iw = rem - ih * 6;
    int h = ih * 8 + (l >> 3), w = iw * 8 + (l & 7);
    int hw = h * 48 + w;

    __shared__ float xs[256];
    xs[tid]       = x[(b * 256 + tid) * 2304 + hw];
    xs[tid + 128] = x[(b * 256 + tid + 128) * 2304 + hw];
    __syncthreads();

    int o0 = tid, o1 = tid + 128;
    float acc0 = pb[o0];
    float acc1 = pb[o1];
    const float* w0 = pw + o0 * 256;
    const float* w1 = pw + o1 * 256;
#pragma unroll 4
    for (int c0 = 0; c0 < 256; c0 += 4) {
        f32x4 a  = *(const f32x4*)(w0 + c0);
        f32x4 bb = *(const f32x4*)(w1 + c0);
        f32x4 xv = *(const f32x4*)&xs[c0];
        acc0 += xv[0]*a[0] + xv[1]*a[1] + xv[2]*a[2] + xv[3]*a[3];
        acc1 += xv[0]*bb[0] + xv[1]*bb[1] + xv[2]*bb[2] + xv[3]*bb[3];
    }
    // LayerNorm over 256 channels (2 per thread, 2 waves)
    float s = acc0 + acc1, s2 = acc0 * acc0 + acc1 * acc1;
#pragma unroll
    for (int off = 32; off; off >>= 1) {
        s  += __shfl_down(s, off);
        s2 += __shfl_down(s2, off);
    }
    __shared__ float red[4];
    if ((tid & 63) == 0) { red[(tid >> 6) * 2] = s; red[(tid >> 6) * 2 + 1] = s2; }
    __syncthreads();
    float S = red[0] + red[2], S2 = red[1] + red[3];
    float m = S * (1.f / 256.f);
    float var = S2 * (1.f / 256.f) - m * m;
    float rstd = rsqrtf(var + 1e-5f);
    t[tok * 256 + o0] = (acc0 - m) * rstd * lg[o0] + lb[o0];
    t[tok * 256 + o1] = (acc1 - m) * rstd * lg[o1] + lb[o1];
}

// ---------------------------------------------------------------------------
// K2: xz = t @ W_in^T per window; chunks 0..7 -> xm half (causal conv4 + SiLU),
// chunks 8..15 -> z half (SiLU only). grid NWIN*16, block 256 (16 et x 16 lt).
// Weights staged as bf16 in LDS (within 2% output threshold).
// ---------------------------------------------------------------------------
__global__ __launch_bounds__(256) void k2_xz(
    const float* __restrict__ t, const float* __restrict__ W_in,
    const float* __restrict__ conv_w, const float* __restrict__ conv_b,
    float* __restrict__ xm, float* __restrict__ sz) {
    __shared__ float tl[64 * 260];   // 66560 B
    __shared__ u16   wl[64 * 260];   // 33280 B
    __shared__ float raw[64 * 65];   // 16640 B (pre-conv xm)
    int wi = blockIdx.x >> 4;
    int e0 = (blockIdx.x & 15) * 64;
    int tid = threadIdx.x;

    const float* tw = t + wi * 16384;
    for (int i = tid; i < 16384; i += 256) tl[(i >> 8) * 260 + (i & 255)] = tw[i];
    const float* wp = W_in + e0 * 256;
    for (int i = tid; i < 16384; i += 256) wl[(i >> 8) * 260 + (i & 255)] = f2bu(wp[i]);
    __syncthreads();

    int et = tid & 15, lt = tid >> 4;
    float acc[4][4] = {};
#pragma unroll 1
    for (int c0 = 0; c0 < 256; c0 += 4) {
        f32x4 tv0 = *(const f32x4*)&tl[(lt * 4 + 0) * 260 + c0];
        f32x4 tv1 = *(const f32x4*)&tl[(lt * 4 + 1) * 260 + c0];
        f32x4 tv2 = *(const f32x4*)&tl[(lt * 4 + 2) * 260 + c0];
        f32x4 tv3 = *(const f32x4*)&tl[(lt * 4 + 3) * 260 + c0];
#pragma unroll
        for (int i = 0; i < 4; i++) {
            u16x4 wv = *(const u16x4*)&wl[(et * 4 + i) * 260 + c0];
            float w0 = bu2f(wv[0]), w1 = bu2f(wv[1]), w2 = bu2f(wv[2]), w3 = bu2f(wv[3]);
            acc[i][0] += w0 * tv0[0] + w1 * tv0[1] + w2 * tv0[2] + w3 * tv0[3];
            acc[i][1] += w0 * tv1[0] + w1 * tv1[1] + w2 * tv1[2] + w3 * tv1[3];
            acc[i][2] += w0 * tv2[0] + w1 * tv2[1] + w2 * tv2[2] + w3 * tv2[3];
            acc[i][3] += w0 * tv3[0] + w1 * tv3[1] + w2 * tv3[2] + w3 * tv3[3];
        }
    }

    if (e0 < 512) {
#pragma unroll
        for (int i = 0; i < 4; i++)
#pragma unroll
            for (int j = 0; j < 4; j++)
                raw[(lt * 4 + j) * 65 + et * 4 + i] = acc[i][j];
        __syncthreads();
#pragma unroll
        for (int i = 0; i < 4; i++) {
            int d = e0 + et * 4 + i;
            float c0w = conv_w[d * 4 + 0], c1w = conv_w[d * 4 + 1];
            float c2w = conv_w[d * 4 + 2], c3w = conv_w[d * 4 + 3];
            float cbv = conv_b[d];
#pragma unroll
            for (int j = 0; j < 4; j++) {
                int l = lt * 4 + j;
                float v = cbv + raw[l * 65 + et * 4 + i] * c3w;
                if (l >= 1) v += raw[(l - 1) * 65 + et * 4 + i] * c2w;
                if (l >= 2) v += raw[(l - 2) * 65 + et * 4 + i] * c1w;
                if (l >= 3) v += raw[(l - 3) * 65 + et * 4 + i] * c0w;
                xm[(wi * 64 + l) * 512 + d] = silu(v);
            }
        }
    } else {
#pragma unroll
        for (int i = 0; i < 4; i++) {
            int zd = e0 - 512 + et * 4 + i;
#pragma unroll
            for (int j = 0; j < 4; j++) {
                int l = lt * 4 + j;
                sz[(wi * 64 + l) * 512 + zd] = silu(acc[i][j]);
            }
        }
    }
}

// ---------------------------------------------------------------------------
// K3: xdb = xm @ W_xproj^T (48 outs), dt = softplus(xdb[:16] @ W_dt^T + b_dt),
// B/C = xdb[16:32]/[32:48]. 4 tokens per block; bf16 weights staged in LDS.
// ---------------------------------------------------------------------------
__global__ __launch_bounds__(256) void k3_dtbc(
    const float* __restrict__ xm, const float* __restrict__ W_xproj,
    const float* __restrict__ W_dt, const float* __restrict__ b_dt,
    float* __restrict__ dt, float* __restrict__ Bm, float* __restrict__ Cm) {
    __shared__ u16 wx[48 * 520];   // 49920 B
    __shared__ u16 wd[512 * 20];   // 20480 B
    __shared__ float xv[512];
    __shared__ float part[192];
    __shared__ float xdb[48];
    int tid = threadIdx.x;
    for (int i = tid; i < 24576; i += 256) wx[(i >> 9) * 520 + (i & 511)] = f2bu(W_xproj[i]);
    for (int i = tid; i < 8192; i += 256)  wd[(i >> 4) * 20 + (i & 15)]   = f2bu(W_dt[i]);

    int tok0 = blockIdx.x * 4;
    for (int tt = 0; tt < 4; tt++) {
        int tok = tok0 + tt;
        __syncthreads();
        for (int i = tid; i < 512; i += 256) xv[i] = xm[tok * 512 + i];
        __syncthreads();
        if (tid < 192) {
            int e = tid >> 2, p = tid & 3;
            const u16* wr = wx + e * 520 + p * 128;
            const float* xr = xv + p * 128;
            float s = 0.f;
#pragma unroll
            for (int c = 0; c < 128; c += 8) {
                u16x8 wv = *(const u16x8*)(wr + c);
                f32x4 a = *(const f32x4*)(xr + c);
                f32x4 b2 = *(const f32x4*)(xr + c + 4);
                s += a[0]*bu2f(wv[0]) + a[1]*bu2f(wv[1]) + a[2]*bu2f(wv[2]) + a[3]*bu2f(wv[3])
                   + b2[0]*bu2f(wv[4]) + b2[1]*bu2f(wv[5]) + b2[2]*bu2f(wv[6]) + b2[3]*bu2f(wv[7]);
            }
            part[tid] = s;
        }
        __syncthreads();
        if (tid < 48) {
            float v = part[tid * 4] + part[tid * 4 + 1] + part[tid * 4 + 2] + part[tid * 4 + 3];
            xdb[tid] = v;
            if (tid >= 32)      Cm[tok * 16 + tid - 32] = v;
            else if (tid >= 16) Bm[tok * 16 + tid - 16] = v;
        }
        __syncthreads();
#pragma unroll
        for (int q = 0; q < 2; q++) {
            int d = tid + q * 256;
            const u16* wr = wd + d * 20;
            float s = b_dt[d];
#pragma unroll
            for (int r = 0; r < 16; r++) s += xdb[r] * bu2f(wr[r]);
            float sp = (s > 20.f) ? s : log1pf(__expf(s));
            dt[tok * 512 + d] = sp;
        }
    }
}

// ---------------------------------------------------------------------------
// K4: selective scan. One block per window, one thread per d (512 threads).
// y written in-place over dt buffer (same-thread read-before-write).
// ---------------------------------------------------------------------------
__global__ __launch_bounds__(512) void k4_scan(
    const float* __restrict__ xm, const float* dt_in,
    const float* __restrict__ Bm, const float* __restrict__ Cm,
    const float* __restrict__ sz, const float* __restrict__ A_log,
    const float* __restrict__ Dp, float* y) {
    int wi = blockIdx.x, d = threadIdx.x;
    __shared__ float lB[1024], lC[1024];
#pragma unroll
    for (int q = 0; q < 2; q++) {
        int i = d + q * 512;
        lB[i] = Bm[wi * 1024 + i];
        lC[i] = Cm[wi * 1024 + i];
    }
    float A[16];
#pragma unroll
    for (int n = 0; n < 16; n++) A[n] = -__expf(A_log[d * 16 + n]);
    float Dd = Dp[d];
    float h[16];
#pragma unroll
    for (int n = 0; n < 16; n++) h[n] = 0.f;
    __syncthreads();
#pragma unroll 1
    for (int l = 0; l < 64; l++) {
        int idx = (wi * 64 + l) * 512 + d;
        float dtv = dt_in[idx];
        float xv  = xm[idx];
        float szv = sz[idx];
        float dx = dtv * xv;
        float yv = 0.f;
#pragma unroll
        for (int n = 0; n < 16; n++) {
            float dA = __expf(dtv * A[n]);
            h[n] = dA * h[n] + dx * lB[l * 16 + n];
            yv += h[n] * lC[l * 16 + n];
        }
        y[idx] = (yv + xv * Dd) * szv;
    }
}

// ---------------------------------------------------------------------------
// K5: ytok = y @ W_out^T  (NTOK x 512) * (256 x 512)^T. 32 tokens x 64 o per block.
// ---------------------------------------------------------------------------
__global__ __launch_bounds__(256) void k5_wout(
    const float* __restrict__ y, const float* __restrict__ W_out,
    float* __restrict__ ytok) {
    __shared__ float yl[32 * 516];   // 66048 B
    __shared__ u16   wl[64 * 516];   // 66048 B
    int tg = blockIdx.x >> 2;
    int o0 = (blockIdx.x & 3) * 64;
    int tid = threadIdx.x;
    int tok0 = tg * 32;

    const float* yp = y + tok0 * 512;
    for (int i = tid; i < 16384; i += 256) yl[(i >> 9) * 516 + (i & 511)] = yp[i];
    const float* wp = W_out + o0 * 512;
    for (int i = tid; i < 32768; i += 256) wl[(i >> 9) * 516 + (i & 511)] = f2bu(wp[i]);
    __syncthreads();

    int ot = tid & 15, lt = tid >> 4;
    float acc[4][2] = {};
#pragma unroll 1
    for (int c0 = 0; c0 < 512; c0 += 4) {
        f32x4 tv0 = *(const f32x4*)&yl[(lt * 2 + 0) * 516 + c0];
        f32x4 tv1 = *(const f32x4*)&yl[(lt * 2 + 1) * 516 + c0];
#pragma unroll
        for (int i = 0; i < 4; i++) {
            u16x4 wv = *(const u16x4*)&wl[(ot * 4 + i) * 516 + c0];
            float w0 = bu2f(wv[0]), w1 = bu2f(wv[1]), w2 = bu2f(wv[2]), w3 = bu2f(wv[3]);
            acc[i][0] += w0 * tv0[0] + w1 * tv0[1] + w2 * tv0[2] + w3 * tv0[3];
            acc[i][1] += w0 * tv1[0] + w1 * tv1[1] + w2 * tv1[2] + w3 * tv1[3];
        }
    }
#pragma unroll
    for (int j = 0; j < 2; j++) {
        int tok = tok0 + lt * 2 + j;
#pragma unroll
        for (int i = 0; i < 4; i++)
            ytok[tok * 256 + o0 + ot * 4 + i] = acc[i][j];
    }
}

// ---------------------------------------------------------------------------
// K6: out = ytok @ proj_out_w^T + b + residual, window-merged to (B,C,H,W) fp32.
// ---------------------------------------------------------------------------
__global__ __launch_bounds__(256) void k6_out(
    const float* __restrict__ ytok, const float* __restrict__ pw,
    const float* __restrict__ pb, const float* __restrict__ xres,
    float* __restrict__ out) {
    __shared__ float yl[32 * 260];   // 33280 B
    __shared__ u16   wl[64 * 260];   // 33280 B
    int tg = blockIdx.x >> 2;
    int o0 = (blockIdx.x & 3) * 64;
    int tid = threadIdx.x;
    int tok0 = tg * 32;

    const float* yp = ytok + tok0 * 256;
    for (int i = tid; i < 8192; i += 256) yl[(i >> 8) * 260 + (i & 255)] = yp[i];
    const float* wp = pw + o0 * 256;
    for (int i = tid; i < 16384; i += 256) wl[(i >> 8) * 260 + (i & 255)] = f2bu(wp[i]);
    __syncthreads();

    int ot = tid & 15, lt = tid >> 4;
    float acc[4][2] = {};
#pragma unroll 1
    for (int c0 = 0; c0 < 256; c0 += 4) {
        f32x4 tv0 = *(const f32x4*)&yl[(lt * 2 + 0) * 260 + c0];
        f32x4 tv1 = *(const f32x4*)&yl[(lt * 2 + 1) * 260 + c0];
#pragma unroll
        for (int i = 0; i < 4; i++) {
            u16x4 wv = *(const u16x4*)&wl[(ot * 4 + i) * 260 + c0];
            float w0 = bu2f(wv[0]), w1 = bu2f(wv[1]), w2 = bu2f(wv[2]), w3 = bu2f(wv[3]);
            acc[i][0] += w0 * tv0[0] + w1 * tv0[1] + w2 * tv0[2] + w3 * tv0[3];
            acc[i][1] += w0 * tv1[0] + w1 * tv1[1] + w2 * tv1[2] + w3 * tv1[3];
        }
    }
#pragma unroll
    for (int j = 0; j < 2; j++) {
        int tok = tok0 + lt * 2 + j;
        int wi = tok >> 6, l = tok & 63;
        int b = wi / 36; int rem = wi - b * 36; int ih = rem / 6; int iw = rem - ih * 6;
        int h = ih * 8 + (l >> 3), w = iw * 8 + (l & 7);
#pragma unroll
        for (int i = 0; i < 4; i++) {
            int o = o0 + ot * 4 + i;
            int gidx = ((b * 256 + o) * 48 + h) * 48 + w;
            out[gidx] = acc[i][j] + pb[o] + xres[gidx];
        }
    }
}

// ---------------------------------------------------------------------------
extern "C" void kernel_launch(void* const* d_in, const int* in_sizes, int n_in,
                              void* d_out, int out_size, void* d_ws, size_t ws_size,
                              hipStream_t stream) {
    (void)in_sizes; (void)n_in; (void)out_size; (void)ws_size;
    const float* x    = (const float*)d_in[0];
    const float* piw  = (const float*)d_in[1];
    const float* pib  = (const float*)d_in[2];
    const float* lng  = (const float*)d_in[3];
    const float* lnb  = (const float*)d_in[4];
    const float* W_in = (const float*)d_in[5];
    const float* cw   = (const float*)d_in[6];
    const float* cb   = (const float*)d_in[7];
    const float* wxp  = (const float*)d_in[8];
    const float* wdt  = (const float*)d_in[9];
    const float* bdt  = (const float*)d_in[10];
    const float* alog = (const float*)d_in[11];
    const float* Dp   = (const float*)d_in[12];
    const float* wout = (const float*)d_in[13];
    const float* pow_ = (const float*)d_in[14];
    const float* pob  = (const float*)d_in[15];
    float* out = (float*)d_out;

    float* ws  = (float*)d_ws;
    float* t   = ws;                       // NTOK*256   (reused as ytok after K5)
    float* xm  = t   + (size_t)NTOK * 256; // NTOK*512
    float* szb = xm  + (size_t)NTOK * 512; // NTOK*512
    float* dty = szb + (size_t)NTOK * 512; // NTOK*512   (dt, overwritten by y in K4)
    float* Bm  = dty + (size_t)NTOK * 512; // NTOK*16
    float* Cm  = Bm  + (size_t)NTOK * 16;  // NTOK*16
    // total ws: 134,479,872 bytes

    hipLaunchKernelGGL(k1_proj_ln, dim3(NTOK), dim3(128), 0, stream, x, piw, pib, lng, lnb, t);
    hipLaunchKernelGGL(k2_xz,      dim3(NWIN * 16), dim3(256), 0, stream, t, W_in, cw, cb, xm, szb);
    hipLaunchKernelGGL(k3_dtbc,    dim3(NTOK / 4), dim3(256), 0, stream, xm, wxp, wdt, bdt, dty, Bm, Cm);
    hipLaunchKernelGGL(k4_scan,    dim3(NWIN), dim3(512), 0, stream, xm, dty, Bm, Cm, szb, alog, Dp, dty);
    hipLaunchKernelGGL(k5_wout,    dim3((NTOK / 32) * 4), dim3(256), 0, stream, dty, wout, t);
    hipLaunchKernelGGL(k6_out,     dim3((NTOK / 32) * 4), dim3(256), 0, stream, t, pow_, pob, x, out);
}

// Round 3
// 525.611 us; speedup vs baseline: 2.7336x; 2.7336x over previous
//
#include <hip/hip_runtime.h>
#include <hip/hip_bf16.h>

// LocalMamba2D: B=8, C=256, H=W=48, win=8 -> 288 windows x 64 tokens.
// D_INNER=512, DSTATE=16, DT_RANK=16, DCONV=4. fp32 I/O; bf16 MFMA GEMMs.

typedef unsigned short u16;
typedef __attribute__((ext_vector_type(8))) unsigned short u16x8;
typedef __attribute__((ext_vector_type(4))) unsigned short u16x4;
typedef __attribute__((ext_vector_type(4))) float f32x4;
typedef __attribute__((ext_vector_type(8))) short s16x8;

#define NTOK 18432
#define NWIN 288

__device__ __forceinline__ float bu2f(u16 u) {
    union { unsigned int i; float f; } v; v.i = ((unsigned int)u) << 16; return v.f;
}
__device__ __forceinline__ u16 f2bu(float f) {
    union { float f; unsigned int i; } v; v.f = f;
    unsigned int i = v.i;
    unsigned int r = (i + 0x7FFFu + ((i >> 16) & 1u)) >> 16;
    return (u16)r;
}
__device__ __forceinline__ float silu(float v) {
    return v * (1.f / (1.f + __expf(-v)));
}

// stage 64 rows x K cols fp32 (row stride ld) -> bf16 LDS rows of (K+8) u16
template<int K>
__device__ __forceinline__ void stage64(const float* __restrict__ src, int ld,
                                        u16* lds, int tid) {
    constexpr int LD = K + 8;
    constexpr int C4 = K / 4;
    for (int i = tid; i < 16 * K; i += 256) {
        int r = i / C4, c = (i % C4) * 4;
        f32x4 v = *(const f32x4*)(src + r * ld + c);
        u16x4 o; o[0] = f2bu(v[0]); o[1] = f2bu(v[1]); o[2] = f2bu(v[2]); o[3] = f2bu(v[3]);
        *(u16x4*)&lds[r * LD + c] = o;
    }
}

// ---------------------------------------------------------------------------
// K1a: proj_in via MFMA. Block = 64 contiguous spatial positions x 64 out ch.
// grid 288*4. Writes xi (token-major, = t buffer) with bias.
// ---------------------------------------------------------------------------
__global__ __launch_bounds__(256) void k1a_proj(
    const float* __restrict__ x, const float* __restrict__ pw,
    const float* __restrict__ pb, float* __restrict__ xi) {
    __shared__ __attribute__((aligned(16))) u16 a_lds[64 * 264];
    __shared__ __attribute__((aligned(16))) u16 b_lds[64 * 264];
    int tid = threadIdx.x;
    int pt = blockIdx.x >> 2;            // 0..287 position tile
    int o0 = (blockIdx.x & 3) * 64;
    int b = pt / 36;
    int hw0 = (pt - b * 36) * 64;

    // A: x[b][c][hw0+pl] -> a_lds[pl][c]  (coalesced reads; strided LDS writes)
    for (int i = tid; i < 16384; i += 256) {
        int c = i >> 6, pl = i & 63;
        a_lds[pl * 264 + c] = f2bu(x[(b * 256 + c) * 2304 + hw0 + pl]);
    }
    stage64<256>(pw + o0 * 256, 256, b_lds, tid);
    __syncthreads();

    int lane = tid & 63, wv = tid >> 6, fr = lane & 15, fq = lane >> 4;
    f32x4 acc[4] = {};
    {
        const u16* ap = a_lds + (wv * 16 + fr) * 264 + fq * 8;
        const u16* bp = b_lds + fr * 264 + fq * 8;
        for (int kk = 0; kk < 256; kk += 32) {
            s16x8 av = *(const s16x8*)(ap + kk);
#pragma unroll
            for (int nt = 0; nt < 4; nt++) {
                s16x8 bv = *(const s16x8*)(bp + nt * 16 * 264 + kk);
                acc[nt] = __builtin_amdgcn_mfma_f32_16x16x32_bf16(av, bv, acc[nt], 0, 0, 0);
            }
        }
    }
    __syncthreads();
    float* tile = (float*)a_lds;         // 64 x 68
#pragma unroll
    for (int nt = 0; nt < 4; nt++)
#pragma unroll
        for (int r = 0; r < 4; r++)
            tile[(wv * 16 + fq * 4 + r) * 68 + nt * 16 + fr] = acc[nt][r];
    __syncthreads();
    for (int i = tid; i < 4096; i += 256) {
        int pl = i >> 6, oc = i & 63;
        int hw = hw0 + pl;
        int h = hw / 48, w = hw - h * 48;
        int wi = b * 36 + (h >> 3) * 6 + (w >> 3);
        int l = (h & 7) * 8 + (w & 7);
        xi[(wi * 64 + l) * 256 + o0 + oc] = tile[pl * 68 + oc] + pb[o0 + oc];
    }
}

// ---------------------------------------------------------------------------
// K1b: LayerNorm in place on xi (= t). One wave per token, lane holds 4 ch.
// grid NTOK/4, block 256.
// ---------------------------------------------------------------------------
__global__ __launch_bounds__(256) void k1b_ln(
    float* __restrict__ t, const float* __restrict__ lg, const float* __restrict__ lb) {
    int tid = threadIdx.x;
    int tok = blockIdx.x * 4 + (tid >> 6);
    int c4 = (tid & 63) * 4;
    f32x4 v = *(const f32x4*)(t + tok * 256 + c4);
    float s = v[0] + v[1] + v[2] + v[3];
    float s2 = v[0]*v[0] + v[1]*v[1] + v[2]*v[2] + v[3]*v[3];
#pragma unroll
    for (int m = 1; m < 64; m <<= 1) {
        s  += __shfl_xor(s, m);
        s2 += __shfl_xor(s2, m);
    }
    float mean = s * (1.f / 256.f);
    float var = s2 * (1.f / 256.f) - mean * mean;
    float rstd = rsqrtf(var + 1e-5f);
    f32x4 g = *(const f32x4*)(lg + c4);
    f32x4 bb = *(const f32x4*)(lb + c4);
    f32x4 o;
#pragma unroll
    for (int j = 0; j < 4; j++) o[j] = (v[j] - mean) * rstd * g[j] + bb[j];
    *(f32x4*)(t + tok * 256 + c4) = o;
}

// ---------------------------------------------------------------------------
// K2: xz = t @ W_in^T via MFMA; e-chunks 0..7 -> conv4+SiLU -> xm,
// chunks 8..15 -> SiLU -> sz. grid NWIN*16, block 256.
// ---------------------------------------------------------------------------
__global__ __launch_bounds__(256) void k2_xz(
    const float* __restrict__ t, const float* __restrict__ W_in,
    const float* __restrict__ conv_w, const float* __restrict__ conv_b,
    float* __restrict__ xm, float* __restrict__ sz) {
    __shared__ __attribute__((aligned(16))) u16 a_lds[64 * 264];
    __shared__ __attribute__((aligned(16))) u16 b_lds[64 * 264];
    int tid = threadIdx.x;
    int wi = blockIdx.x >> 4;
    int e0 = (blockIdx.x & 15) * 64;

    stage64<256>(t + wi * 16384, 256, a_lds, tid);
    stage64<256>(W_in + e0 * 256, 256, b_lds, tid);
    __syncthreads();

    int lane = tid & 63, wv = tid >> 6, fr = lane & 15, fq = lane >> 4;
    f32x4 acc[4] = {};
    {
        const u16* ap = a_lds + (wv * 16 + fr) * 264 + fq * 8;
        const u16* bp = b_lds + fr * 264 + fq * 8;
        for (int kk = 0; kk < 256; kk += 32) {
            s16x8 av = *(const s16x8*)(ap + kk);
#pragma unroll
            for (int nt = 0; nt < 4; nt++) {
                s16x8 bv = *(const s16x8*)(bp + nt * 16 * 264 + kk);
                acc[nt] = __builtin_amdgcn_mfma_f32_16x16x32_bf16(av, bv, acc[nt], 0, 0, 0);
            }
        }
    }

    if (e0 < 512) {
        __syncthreads();
        float* raw = (float*)a_lds;      // 64 x 68
#pragma unroll
        for (int nt = 0; nt < 4; nt++)
#pragma unroll
            for (int r = 0; r < 4; r++)
                raw[(wv * 16 + fq * 4 + r) * 68 + nt * 16 + fr] = acc[nt][r];
        __syncthreads();
        int dl = tid & 63;
        int d = e0 + dl;
        f32x4 cw4 = *(const f32x4*)(conv_w + d * 4);
        float cbv = conv_b[d];
#pragma unroll
        for (int it = 0; it < 16; it++) {
            int l = (tid >> 6) + it * 4;
            float v = cbv + raw[l * 68 + dl] * cw4[3];
            if (l >= 1) v += raw[(l - 1) * 68 + dl] * cw4[2];
            if (l >= 2) v += raw[(l - 2) * 68 + dl] * cw4[1];
            if (l >= 3) v += raw[(l - 3) * 68 + dl] * cw4[0];
            xm[(wi * 64 + l) * 512 + d] = silu(v);
        }
    } else {
        int z0 = e0 - 512;
#pragma unroll
        for (int nt = 0; nt < 4; nt++)
#pragma unroll
            for (int r = 0; r < 4; r++) {
                int l = wv * 16 + fq * 4 + r;
                sz[(wi * 64 + l) * 512 + z0 + nt * 16 + fr] = silu(acc[nt][r]);
            }
    }
}

// ---------------------------------------------------------------------------
// K3: xdb = xm @ W_xproj^T (48), dt = softplus(xdb[:16] @ W_dt^T + b_dt),
// B/C out. 4 tokens per block (vector; convert to MFMA if hot next round).
// ---------------------------------------------------------------------------
__global__ __launch_bounds__(256) void k3_dtbc(
    const float* __restrict__ xm, const float* __restrict__ W_xproj,
    const float* __restrict__ W_dt, const float* __restrict__ b_dt,
    float* __restrict__ dt, float* __restrict__ Bm, float* __restrict__ Cm) {
    __shared__ u16 wx[48 * 520];
    __shared__ u16 wd[512 * 20];
    __shared__ float xv[512];
    __shared__ float part[192];
    __shared__ float xdb[48];
    int tid = threadIdx.x;
    for (int i = tid; i < 24576; i += 256) wx[(i >> 9) * 520 + (i & 511)] = f2bu(W_xproj[i]);
    for (int i = tid; i < 8192; i += 256)  wd[(i >> 4) * 20 + (i & 15)]   = f2bu(W_dt[i]);

    int tok0 = blockIdx.x * 4;
    for (int tt = 0; tt < 4; tt++) {
        int tok = tok0 + tt;
        __syncthreads();
        for (int i = tid; i < 512; i += 256) xv[i] = xm[tok * 512 + i];
        __syncthreads();
        if (tid < 192) {
            int e = tid >> 2, p = tid & 3;
            const u16* wr = wx + e * 520 + p * 128;
            const float* xr = xv + p * 128;
            float s = 0.f;
#pragma unroll
            for (int c = 0; c < 128; c += 8) {
                u16x8 wv = *(const u16x8*)(wr + c);
                f32x4 a = *(const f32x4*)(xr + c);
                f32x4 b2 = *(const f32x4*)(xr + c + 4);
                s += a[0]*bu2f(wv[0]) + a[1]*bu2f(wv[1]) + a[2]*bu2f(wv[2]) + a[3]*bu2f(wv[3])
                   + b2[0]*bu2f(wv[4]) + b2[1]*bu2f(wv[5]) + b2[2]*bu2f(wv[6]) + b2[3]*bu2f(wv[7]);
            }
            part[tid] = s;
        }
        __syncthreads();
        if (tid < 48) {
            float v = part[tid * 4] + part[tid * 4 + 1] + part[tid * 4 + 2] + part[tid * 4 + 3];
            xdb[tid] = v;
            if (tid >= 32)      Cm[tok * 16 + tid - 32] = v;
            else if (tid >= 16) Bm[tok * 16 + tid - 16] = v;
        }
        __syncthreads();
#pragma unroll
        for (int q = 0; q < 2; q++) {
            int d = tid + q * 256;
            const u16* wr = wd + d * 20;
            float s = b_dt[d];
#pragma unroll
            for (int r = 0; r < 16; r++) s += xdb[r] * bu2f(wr[r]);
            float sp = (s > 20.f) ? s : log1pf(__expf(s));
            dt[tok * 512 + d] = sp;
        }
    }
}

// ---------------------------------------------------------------------------
// K4: selective scan. One block per window, one thread per d.
// ---------------------------------------------------------------------------
__global__ __launch_bounds__(512) void k4_scan(
    const float* __restrict__ xm, const float* dt_in,
    const float* __restrict__ Bm, const float* __restrict__ Cm,
    const float* __restrict__ sz, const float* __restrict__ A_log,
    const float* __restrict__ Dp, float* y) {
    int wi = blockIdx.x, d = threadIdx.x;
    __shared__ float lB[1024], lC[1024];
#pragma unroll
    for (int q = 0; q < 2; q++) {
        int i = d + q * 512;
        lB[i] = Bm[wi * 1024 + i];
        lC[i] = Cm[wi * 1024 + i];
    }
    float A[16];
#pragma unroll
    for (int n = 0; n < 16; n++) A[n] = -__expf(A_log[d * 16 + n]);
    float Dd = Dp[d];
    float h[16];
#pragma unroll
    for (int n = 0; n < 16; n++) h[n] = 0.f;
    __syncthreads();
#pragma unroll 1
    for (int l = 0; l < 64; l++) {
        int idx = (wi * 64 + l) * 512 + d;
        float dtv = dt_in[idx];
        float xv  = xm[idx];
        float szv = sz[idx];
        float dx = dtv * xv;
        float yv = 0.f;
#pragma unroll
        for (int n = 0; n < 16; n++) {
            float dA = __expf(dtv * A[n]);
            h[n] = dA * h[n] + dx * lB[l * 16 + n];
            yv += h[n] * lC[l * 16 + n];
        }
        y[idx] = (yv + xv * Dd) * szv;
    }
}

// ---------------------------------------------------------------------------
// K5: ytok = y @ W_out^T via MFMA (K=512). grid NWIN*4, block 256.
// ---------------------------------------------------------------------------
__global__ __launch_bounds__(256) void k5_wout(
    const float* __restrict__ y, const float* __restrict__ W_out,
    float* __restrict__ ytok) {
    __shared__ __attribute__((aligned(16))) u16 a_lds[64 * 520];
    __shared__ __attribute__((aligned(16))) u16 b_lds[64 * 520];
    int tid = threadIdx.x;
    int wi = blockIdx.x >> 2;
    int o0 = (blockIdx.x & 3) * 64;

    stage64<512>(y + wi * 32768, 512, a_lds, tid);
    stage64<512>(W_out + o0 * 512, 512, b_lds, tid);
    __syncthreads();

    int lane = tid & 63, wv = tid >> 6, fr = lane & 15, fq = lane >> 4;
    f32x4 acc[4] = {};
    {
        const u16* ap = a_lds + (wv * 16 + fr) * 520 + fq * 8;
        const u16* bp = b_lds + fr * 520 + fq * 8;
        for (int kk = 0; kk < 512; kk += 32) {
            s16x8 av = *(const s16x8*)(ap + kk);
#pragma unroll
            for (int nt = 0; nt < 4; nt++) {
                s16x8 bv = *(const s16x8*)(bp + nt * 16 * 520 + kk);
                acc[nt] = __builtin_amdgcn_mfma_f32_16x16x32_bf16(av, bv, acc[nt], 0, 0, 0);
            }
        }
    }
#pragma unroll
    for (int nt = 0; nt < 4; nt++)
#pragma unroll
        for (int r = 0; r < 4; r++) {
            int l = wv * 16 + fq * 4 + r;
            ytok[(wi * 64 + l) * 256 + o0 + nt * 16 + fr] = acc[nt][r];
        }
}

// ---------------------------------------------------------------------------
// K6: out = ytok @ proj_out_w^T + b + residual, window-merged. grid NWIN*4.
// ---------------------------------------------------------------------------
__global__ __launch_bounds__(256) void k6_out(
    const float* __restrict__ ytok, const float* __restrict__ pw,
    const float* __restrict__ pb, const float* __restrict__ xres,
    float* __restrict__ out) {
    __shared__ __attribute__((aligned(16))) u16 a_lds[64 * 264];
    __shared__ __attribute__((aligned(16))) u16 b_lds[64 * 264];
    int tid = threadIdx.x;
    int wi = blockIdx.x >> 2;
    int o0 = (blockIdx.x & 3) * 64;

    stage64<256>(ytok + wi * 16384, 256, a_lds, tid);
    stage64<256>(pw + o0 * 256, 256, b_lds, tid);
    __syncthreads();

    int lane = tid & 63, wv = tid >> 6, fr = lane & 15, fq = lane >> 4;
    f32x4 acc[4] = {};
    {
        const u16* ap = a_lds + (wv * 16 + fr) * 264 + fq * 8;
        const u16* bp = b_lds + fr * 264 + fq * 8;
        for (int kk = 0; kk < 256; kk += 32) {
            s16x8 av = *(const s16x8*)(ap + kk);
#pragma unroll
            for (int nt = 0; nt < 4; nt++) {
                s16x8 bv = *(const s16x8*)(bp + nt * 16 * 264 + kk);
                acc[nt] = __builtin_amdgcn_mfma_f32_16x16x32_bf16(av, bv, acc[nt], 0, 0, 0);
            }
        }
    }
    __syncthreads();
    float* tile = (float*)a_lds;         // 64 x 68
#pragma unroll
    for (int nt = 0; nt < 4; nt++)
#pragma unroll
        for (int r = 0; r < 4; r++)
            tile[(wv * 16 + fq * 4 + r) * 68 + nt * 16 + fr] = acc[nt][r];
    __syncthreads();

    int b = wi / 36; int rem = wi - b * 36; int ih = rem / 6; int iw = rem - ih * 6;
    for (int i = tid; i < 4096; i += 256) {
        int oc = i >> 6, l = i & 63;
        int h = ih * 8 + (l >> 3), w = iw * 8 + (l & 7);
        int o = o0 + oc;
        int gidx = ((b * 256 + o) * 48 + h) * 48 + w;
        out[gidx] = tile[l * 68 + oc] + pb[o] + xres[gidx];
    }
}

// ---------------------------------------------------------------------------
extern "C" void kernel_launch(void* const* d_in, const int* in_sizes, int n_in,
                              void* d_out, int out_size, void* d_ws, size_t ws_size,
                              hipStream_t stream) {
    (void)in_sizes; (void)n_in; (void)out_size; (void)ws_size;
    const float* x    = (const float*)d_in[0];
    const float* piw  = (const float*)d_in[1];
    const float* pib  = (const float*)d_in[2];
    const float* lng  = (const float*)d_in[3];
    const float* lnb  = (const float*)d_in[4];
    const float* W_in = (const float*)d_in[5];
    const float* cw   = (const float*)d_in[6];
    const float* cb   = (const float*)d_in[7];
    const float* wxp  = (const float*)d_in[8];
    const float* wdt  = (const float*)d_in[9];
    const float* bdt  = (const float*)d_in[10];
    const float* alog = (const float*)d_in[11];
    const float* Dp   = (const float*)d_in[12];
    const float* wout = (const float*)d_in[13];
    const float* pow_ = (const float*)d_in[14];
    const float* pob  = (const float*)d_in[15];
    float* out = (float*)d_out;

    float* ws  = (float*)d_ws;
    float* t   = ws;                       // NTOK*256 (xi -> t in place; ytok after K5)
    float* xm  = t   + (size_t)NTOK * 256; // NTOK*512
    float* szb = xm  + (size_t)NTOK * 512; // NTOK*512
    float* dty = szb + (size_t)NTOK * 512; // NTOK*512 (dt, overwritten by y in K4)
    float* Bm  = dty + (size_t)NTOK * 512; // NTOK*16
    float* Cm  = Bm  + (size_t)NTOK * 16;  // NTOK*16

    hipLaunchKernelGGL(k1a_proj, dim3(NWIN * 4), dim3(256), 0, stream, x, piw, pib, t);
    hipLaunchKernelGGL(k1b_ln,   dim3(NTOK / 4), dim3(256), 0, stream, t, lng, lnb);
    hipLaunchKernelGGL(k2_xz,    dim3(NWIN * 16), dim3(256), 0, stream, t, W_in, cw, cb, xm, szb);
    hipLaunchKernelGGL(k3_dtbc,  dim3(NTOK / 4), dim3(256), 0, stream, xm, wxp, wdt, bdt, dty, Bm, Cm);
    hipLaunchKernelGGL(k4_scan,  dim3(NWIN), dim3(512), 0, stream, xm, dty, Bm, Cm, szb, alog, Dp, dty);
    hipLaunchKernelGGL(k5_wout,  dim3(NWIN * 4), dim3(256), 0, stream, dty, wout, t);
    hipLaunchKernelGGL(k6_out,   dim3(NWIN * 4), dim3(256), 0, stream, t, pow_, pob, x, out);
}

// Round 4
// 451.256 us; speedup vs baseline: 3.1840x; 1.1648x over previous
//
#include <hip/hip_runtime.h>
#include <hip/hip_bf16.h>

// LocalMamba2D: B=8, C=256, H=W=48, win=8 -> 288 windows x 64 tokens.
// D_INNER=512, DSTATE=16, DT_RANK=16, DCONV=4. fp32 I/O; bf16 MFMA GEMMs.

typedef unsigned short u16;
typedef __attribute__((ext_vector_type(8))) unsigned short u16x8;
typedef __attribute__((ext_vector_type(4))) unsigned short u16x4;
typedef __attribute__((ext_vector_type(4))) float f32x4;
typedef __attribute__((ext_vector_type(8))) short s16x8;

#define NTOK 18432
#define NWIN 288

__device__ __forceinline__ float bu2f(u16 u) {
    union { unsigned int i; float f; } v; v.i = ((unsigned int)u) << 16; return v.f;
}
__device__ __forceinline__ u16 f2bu(float f) {
    union { float f; unsigned int i; } v; v.f = f;
    unsigned int i = v.i;
    unsigned int r = (i + 0x7FFFu + ((i >> 16) & 1u)) >> 16;
    return (u16)r;
}
__device__ __forceinline__ float silu(float v) {
    return v * (1.f / (1.f + __expf(-v)));
}
__device__ __forceinline__ s16x8 pack8(f32x4 a, f32x4 b) {
    s16x8 o;
    o[0] = (short)f2bu(a[0]); o[1] = (short)f2bu(a[1]);
    o[2] = (short)f2bu(a[2]); o[3] = (short)f2bu(a[3]);
    o[4] = (short)f2bu(b[0]); o[5] = (short)f2bu(b[1]);
    o[6] = (short)f2bu(b[2]); o[7] = (short)f2bu(b[3]);
    return o;
}

// stage 64 rows x K cols fp32 (row stride ld) -> bf16 LDS rows of (K+8) u16
template<int K>
__device__ __forceinline__ void stage64(const float* __restrict__ src, int ld,
                                        u16* lds, int tid) {
    constexpr int LD = K + 8;
    constexpr int C4 = K / 4;
    for (int i = tid; i < 16 * K; i += 256) {
        int r = i / C4, c = (i % C4) * 4;
        f32x4 v = *(const f32x4*)(src + r * ld + c);
        u16x4 o; o[0] = f2bu(v[0]); o[1] = f2bu(v[1]); o[2] = f2bu(v[2]); o[3] = f2bu(v[3]);
        *(u16x4*)&lds[r * LD + c] = o;
    }
}

// ---------------------------------------------------------------------------
// K1a: proj_in via MFMA. Block = 64 contiguous spatial positions x 64 out ch.
// ---------------------------------------------------------------------------
__global__ __launch_bounds__(256) void k1a_proj(
    const float* __restrict__ x, const float* __restrict__ pw,
    const float* __restrict__ pb, float* __restrict__ xi) {
    __shared__ __attribute__((aligned(16))) u16 a_lds[64 * 264];
    __shared__ __attribute__((aligned(16))) u16 b_lds[64 * 264];
    int tid = threadIdx.x;
    int pt = blockIdx.x >> 2;
    int o0 = (blockIdx.x & 3) * 64;
    int b = pt / 36;
    int hw0 = (pt - b * 36) * 64;

    for (int i = tid; i < 16384; i += 256) {
        int c = i >> 6, pl = i & 63;
        a_lds[pl * 264 + c] = f2bu(x[(b * 256 + c) * 2304 + hw0 + pl]);
    }
    stage64<256>(pw + o0 * 256, 256, b_lds, tid);
    __syncthreads();

    int lane = tid & 63, wv = tid >> 6, fr = lane & 15, fq = lane >> 4;
    f32x4 acc[4] = {};
    {
        const u16* ap = a_lds + (wv * 16 + fr) * 264 + fq * 8;
        const u16* bp = b_lds + fr * 264 + fq * 8;
        for (int kk = 0; kk < 256; kk += 32) {
            s16x8 av = *(const s16x8*)(ap + kk);
#pragma unroll
            for (int nt = 0; nt < 4; nt++) {
                s16x8 bv = *(const s16x8*)(bp + nt * 16 * 264 + kk);
                acc[nt] = __builtin_amdgcn_mfma_f32_16x16x32_bf16(av, bv, acc[nt], 0, 0, 0);
            }
        }
    }
    __syncthreads();
    float* tile = (float*)a_lds;         // 64 x 68
#pragma unroll
    for (int nt = 0; nt < 4; nt++)
#pragma unroll
        for (int r = 0; r < 4; r++)
            tile[(wv * 16 + fq * 4 + r) * 68 + nt * 16 + fr] = acc[nt][r];
    __syncthreads();
    for (int i = tid; i < 4096; i += 256) {
        int pl = i >> 6, oc = i & 63;
        int hw = hw0 + pl;
        int h = hw / 48, w = hw - h * 48;
        int wi = b * 36 + (h >> 3) * 6 + (w >> 3);
        int l = (h & 7) * 8 + (w & 7);
        xi[(wi * 64 + l) * 256 + o0 + oc] = tile[pl * 68 + oc] + pb[o0 + oc];
    }
}

// ---------------------------------------------------------------------------
// K1b: LayerNorm in place on xi (= t). One wave per token.
// ---------------------------------------------------------------------------
__global__ __launch_bounds__(256) void k1b_ln(
    float* __restrict__ t, const float* __restrict__ lg, const float* __restrict__ lb) {
    int tid = threadIdx.x;
    int tok = blockIdx.x * 4 + (tid >> 6);
    int c4 = (tid & 63) * 4;
    f32x4 v = *(const f32x4*)(t + tok * 256 + c4);
    float s = v[0] + v[1] + v[2] + v[3];
    float s2 = v[0]*v[0] + v[1]*v[1] + v[2]*v[2] + v[3]*v[3];
#pragma unroll
    for (int m = 1; m < 64; m <<= 1) {
        s  += __shfl_xor(s, m);
        s2 += __shfl_xor(s2, m);
    }
    float mean = s * (1.f / 256.f);
    float var = s2 * (1.f / 256.f) - mean * mean;
    float rstd = rsqrtf(var + 1e-5f);
    f32x4 g = *(const f32x4*)(lg + c4);
    f32x4 bb = *(const f32x4*)(lb + c4);
    f32x4 o;
#pragma unroll
    for (int j = 0; j < 4; j++) o[j] = (v[j] - mean) * rstd * g[j] + bb[j];
    *(f32x4*)(t + tok * 256 + c4) = o;
}

// ---------------------------------------------------------------------------
// K2: xz = t @ W_in^T via MFMA; e-chunks 0..7 -> conv4+SiLU -> xm,
// chunks 8..15 -> SiLU -> sz. grid NWIN*16, block 256.
// ---------------------------------------------------------------------------
__global__ __launch_bounds__(256) void k2_xz(
    const float* __restrict__ t, const float* __restrict__ W_in,
    const float* __restrict__ conv_w, const float* __restrict__ conv_b,
    float* __restrict__ xm, float* __restrict__ sz) {
    __shared__ __attribute__((aligned(16))) u16 a_lds[64 * 264];
    __shared__ __attribute__((aligned(16))) u16 b_lds[64 * 264];
    int tid = threadIdx.x;
    int wi = blockIdx.x >> 4;
    int e0 = (blockIdx.x & 15) * 64;

    stage64<256>(t + wi * 16384, 256, a_lds, tid);
    stage64<256>(W_in + e0 * 256, 256, b_lds, tid);
    __syncthreads();

    int lane = tid & 63, wv = tid >> 6, fr = lane & 15, fq = lane >> 4;
    f32x4 acc[4] = {};
    {
        const u16* ap = a_lds + (wv * 16 + fr) * 264 + fq * 8;
        const u16* bp = b_lds + fr * 264 + fq * 8;
        for (int kk = 0; kk < 256; kk += 32) {
            s16x8 av = *(const s16x8*)(ap + kk);
#pragma unroll
            for (int nt = 0; nt < 4; nt++) {
                s16x8 bv = *(const s16x8*)(bp + nt * 16 * 264 + kk);
                acc[nt] = __builtin_amdgcn_mfma_f32_16x16x32_bf16(av, bv, acc[nt], 0, 0, 0);
            }
        }
    }

    if (e0 < 512) {
        __syncthreads();
        float* raw = (float*)a_lds;      // 64 x 68
#pragma unroll
        for (int nt = 0; nt < 4; nt++)
#pragma unroll
            for (int r = 0; r < 4; r++)
                raw[(wv * 16 + fq * 4 + r) * 68 + nt * 16 + fr] = acc[nt][r];
        __syncthreads();
        int dl = tid & 63;
        int d = e0 + dl;
        f32x4 cw4 = *(const f32x4*)(conv_w + d * 4);
        float cbv = conv_b[d];
#pragma unroll
        for (int it = 0; it < 16; it++) {
            int l = (tid >> 6) + it * 4;
            float v = cbv + raw[l * 68 + dl] * cw4[3];
            if (l >= 1) v += raw[(l - 1) * 68 + dl] * cw4[2];
            if (l >= 2) v += raw[(l - 2) * 68 + dl] * cw4[1];
            if (l >= 3) v += raw[(l - 3) * 68 + dl] * cw4[0];
            xm[(wi * 64 + l) * 512 + d] = silu(v);
        }
    } else {
        int z0 = e0 - 512;
#pragma unroll
        for (int nt = 0; nt < 4; nt++)
#pragma unroll
            for (int r = 0; r < 4; r++) {
                int l = wv * 16 + fq * 4 + r;
                sz[(wi * 64 + l) * 512 + z0 + nt * 16 + fr] = silu(acc[nt][r]);
            }
    }
}

// ---------------------------------------------------------------------------
// K3 (MFMA rewrite): per window (grid NWIN, block 256).
// GEMM1: xdb[64x48] = xm_win @ W_xproj^T (K=512), A staged bf16 in LDS,
//        B frags per-lane from global (L2-hot). e 16..31 -> Bm, 32..47 -> Cm.
// GEMM2: dt[64x512] = xdb[:, :16] @ W_dt^T (K=16 zero-padded to 32) via LDS
//        bounce of xdb; +b_dt, softplus fused.
// ---------------------------------------------------------------------------
__global__ __launch_bounds__(256) void k3_dtbc(
    const float* __restrict__ xm, const float* __restrict__ W_xproj,
    const float* __restrict__ W_dt, const float* __restrict__ b_dt,
    float* __restrict__ dt, float* __restrict__ Bm, float* __restrict__ Cm) {
    __shared__ __attribute__((aligned(16))) u16 a_lds[64 * 520];   // 66560 B
    __shared__ __attribute__((aligned(16))) u16 xdb_lds[64 * 40];  // 5120 B
    int tid = threadIdx.x;
    int wi = blockIdx.x;

    stage64<512>(xm + (size_t)wi * 32768, 512, a_lds, tid);
    {   // zero xdb_lds (cols 16..31 must be 0 for the padded K)
        u16x8 z = {};
        for (int i = tid; i < 320; i += 256) ((u16x8*)xdb_lds)[i] = z;
    }
    __syncthreads();

    int lane = tid & 63, wv = tid >> 6, fr = lane & 15, fq = lane >> 4;

    // ---- GEMM1: M-slice = wave's 16 tokens, N = 48 (3 tiles), K = 512
    f32x4 acc[3] = {};
    {
        const u16* ap = a_lds + (wv * 16 + fr) * 520 + fq * 8;
        const float* bgp = W_xproj + fr * 512 + fq * 8;
        for (int kk = 0; kk < 512; kk += 32) {
            s16x8 av = *(const s16x8*)(ap + kk);
#pragma unroll
            for (int nt = 0; nt < 3; nt++) {
                f32x4 b0 = *(const f32x4*)(bgp + nt * 16 * 512 + kk);
                f32x4 b1 = *(const f32x4*)(bgp + nt * 16 * 512 + kk + 4);
                acc[nt] = __builtin_amdgcn_mfma_f32_16x16x32_bf16(av, pack8(b0, b1), acc[nt], 0, 0, 0);
            }
        }
    }
    // scatter: nt0 -> xdb_lds (bf16), nt1 -> Bm, nt2 -> Cm
#pragma unroll
    for (int r = 0; r < 4; r++) {
        int l = wv * 16 + fq * 4 + r;
        xdb_lds[l * 40 + fr] = f2bu(acc[0][r]);
        Bm[(size_t)(wi * 64 + l) * 16 + fr] = acc[1][r];
        Cm[(size_t)(wi * 64 + l) * 16 + fr] = acc[2][r];
    }
    __syncthreads();

    // ---- GEMM2: M-slice = wave's 16 tokens, N = 512 (4 chunks x 8 tiles), K=32 (16 padded)
    s16x8 av2 = *(const s16x8*)(xdb_lds + (wv * 16 + fr) * 40 + fq * 8);
#pragma unroll 1
    for (int c = 0; c < 4; c++) {
        f32x4 acc2[8] = {};
#pragma unroll
        for (int nt = 0; nt < 8; nt++) {
            s16x8 bv = {};
            if (fq < 2) {
                int d = c * 128 + nt * 16 + fr;
                f32x4 b0 = *(const f32x4*)(W_dt + d * 16 + fq * 8);
                f32x4 b1 = *(const f32x4*)(W_dt + d * 16 + fq * 8 + 4);
                bv = pack8(b0, b1);
            }
            acc2[nt] = __builtin_amdgcn_mfma_f32_16x16x32_bf16(av2, bv, acc2[nt], 0, 0, 0);
        }
#pragma unroll
        for (int nt = 0; nt < 8; nt++) {
            int d = c * 128 + nt * 16 + fr;
            float bdv = b_dt[d];
#pragma unroll
            for (int r = 0; r < 4; r++) {
                int l = wv * 16 + fq * 4 + r;
                float s = acc2[nt][r] + bdv;
                float sp = (s > 20.f) ? s : log1pf(__expf(s));
                dt[(size_t)(wi * 64 + l) * 512 + d] = sp;
            }
        }
    }
}

// ---------------------------------------------------------------------------
// K4: selective scan. One block per window, one thread per d.
// ---------------------------------------------------------------------------
__global__ __launch_bounds__(512) void k4_scan(
    const float* __restrict__ xm, const float* dt_in,
    const float* __restrict__ Bm, const float* __restrict__ Cm,
    const float* __restrict__ sz, const float* __restrict__ A_log,
    const float* __restrict__ Dp, float* y) {
    int wi = blockIdx.x, d = threadIdx.x;
    __shared__ float lB[1024], lC[1024];
#pragma unroll
    for (int q = 0; q < 2; q++) {
        int i = d + q * 512;
        lB[i] = Bm[wi * 1024 + i];
        lC[i] = Cm[wi * 1024 + i];
    }
    float A[16];
#pragma unroll
    for (int n = 0; n < 16; n++) A[n] = -__expf(A_log[d * 16 + n]);
    float Dd = Dp[d];
    float h[16];
#pragma unroll
    for (int n = 0; n < 16; n++) h[n] = 0.f;
    __syncthreads();
#pragma unroll 1
    for (int l = 0; l < 64; l++) {
        int idx = (wi * 64 + l) * 512 + d;
        float dtv = dt_in[idx];
        float xv  = xm[idx];
        float szv = sz[idx];
        float dx = dtv * xv;
        float yv = 0.f;
#pragma unroll
        for (int n = 0; n < 16; n++) {
            float dA = __expf(dtv * A[n]);
            h[n] = dA * h[n] + dx * lB[l * 16 + n];
            yv += h[n] * lC[l * 16 + n];
        }
        y[idx] = (yv + xv * Dd) * szv;
    }
}

// ---------------------------------------------------------------------------
// K5: ytok = y @ W_out^T via MFMA (K=512). grid NWIN*4, block 256.
// ---------------------------------------------------------------------------
__global__ __launch_bounds__(256) void k5_wout(
    const float* __restrict__ y, const float* __restrict__ W_out,
    float* __restrict__ ytok) {
    __shared__ __attribute__((aligned(16))) u16 a_lds[64 * 520];
    __shared__ __attribute__((aligned(16))) u16 b_lds[64 * 520];
    int tid = threadIdx.x;
    int wi = blockIdx.x >> 2;
    int o0 = (blockIdx.x & 3) * 64;

    stage64<512>(y + wi * 32768, 512, a_lds, tid);
    stage64<512>(W_out + o0 * 512, 512, b_lds, tid);
    __syncthreads();

    int lane = tid & 63, wv = tid >> 6, fr = lane & 15, fq = lane >> 4;
    f32x4 acc[4] = {};
    {
        const u16* ap = a_lds + (wv * 16 + fr) * 520 + fq * 8;
        const u16* bp = b_lds + fr * 520 + fq * 8;
        for (int kk = 0; kk < 512; kk += 32) {
            s16x8 av = *(const s16x8*)(ap + kk);
#pragma unroll
            for (int nt = 0; nt < 4; nt++) {
                s16x8 bv = *(const s16x8*)(bp + nt * 16 * 520 + kk);
                acc[nt] = __builtin_amdgcn_mfma_f32_16x16x32_bf16(av, bv, acc[nt], 0, 0, 0);
            }
        }
    }
#pragma unroll
    for (int nt = 0; nt < 4; nt++)
#pragma unroll
        for (int r = 0; r < 4; r++) {
            int l = wv * 16 + fq * 4 + r;
            ytok[(wi * 64 + l) * 256 + o0 + nt * 16 + fr] = acc[nt][r];
        }
}

// ---------------------------------------------------------------------------
// K6: out = ytok @ proj_out_w^T + b + residual, window-merged. grid NWIN*4.
// ---------------------------------------------------------------------------
__global__ __launch_bounds__(256) void k6_out(
    const float* __restrict__ ytok, const float* __restrict__ pw,
    const float* __restrict__ pb, const float* __restrict__ xres,
    float* __restrict__ out) {
    __shared__ __attribute__((aligned(16))) u16 a_lds[64 * 264];
    __shared__ __attribute__((aligned(16))) u16 b_lds[64 * 264];
    int tid = threadIdx.x;
    int wi = blockIdx.x >> 2;
    int o0 = (blockIdx.x & 3) * 64;

    stage64<256>(ytok + wi * 16384, 256, a_lds, tid);
    stage64<256>(pw + o0 * 256, 256, b_lds, tid);
    __syncthreads();

    int lane = tid & 63, wv = tid >> 6, fr = lane & 15, fq = lane >> 4;
    f32x4 acc[4] = {};
    {
        const u16* ap = a_lds + (wv * 16 + fr) * 264 + fq * 8;
        const u16* bp = b_lds + fr * 264 + fq * 8;
        for (int kk = 0; kk < 256; kk += 32) {
            s16x8 av = *(const s16x8*)(ap + kk);
#pragma unroll
            for (int nt = 0; nt < 4; nt++) {
                s16x8 bv = *(const s16x8*)(bp + nt * 16 * 264 + kk);
                acc[nt] = __builtin_amdgcn_mfma_f32_16x16x32_bf16(av, bv, acc[nt], 0, 0, 0);
            }
        }
    }
    __syncthreads();
    float* tile = (float*)a_lds;         // 64 x 68
#pragma unroll
    for (int nt = 0; nt < 4; nt++)
#pragma unroll
        for (int r = 0; r < 4; r++)
            tile[(wv * 16 + fq * 4 + r) * 68 + nt * 16 + fr] = acc[nt][r];
    __syncthreads();

    int b = wi / 36; int rem = wi - b * 36; int ih = rem / 6; int iw = rem - ih * 6;
    for (int i = tid; i < 4096; i += 256) {
        int oc = i >> 6, l = i & 63;
        int h = ih * 8 + (l >> 3), w = iw * 8 + (l & 7);
        int o = o0 + oc;
        int gidx = ((b * 256 + o) * 48 + h) * 48 + w;
        out[gidx] = tile[l * 68 + oc] + pb[o] + xres[gidx];
    }
}

// ---------------------------------------------------------------------------
extern "C" void kernel_launch(void* const* d_in, const int* in_sizes, int n_in,
                              void* d_out, int out_size, void* d_ws, size_t ws_size,
                              hipStream_t stream) {
    (void)in_sizes; (void)n_in; (void)out_size; (void)ws_size;
    const float* x    = (const float*)d_in[0];
    const float* piw  = (const float*)d_in[1];
    const float* pib  = (const float*)d_in[2];
    const float* lng  = (const float*)d_in[3];
    const float* lnb  = (const float*)d_in[4];
    const float* W_in = (const float*)d_in[5];
    const float* cw   = (const float*)d_in[6];
    const float* cb   = (const float*)d_in[7];
    const float* wxp  = (const float*)d_in[8];
    const float* wdt  = (const float*)d_in[9];
    const float* bdt  = (const float*)d_in[10];
    const float* alog = (const float*)d_in[11];
    const float* Dp   = (const float*)d_in[12];
    const float* wout = (const float*)d_in[13];
    const float* pow_ = (const float*)d_in[14];
    const float* pob  = (const float*)d_in[15];
    float* out = (float*)d_out;

    float* ws  = (float*)d_ws;
    float* t   = ws;                       // NTOK*256 (xi -> t in place; ytok after K5)
    float* xm  = t   + (size_t)NTOK * 256; // NTOK*512
    float* szb = xm  + (size_t)NTOK * 512; // NTOK*512
    float* dty = szb + (size_t)NTOK * 512; // NTOK*512 (dt, overwritten by y in K4)
    float* Bm  = dty + (size_t)NTOK * 512; // NTOK*16
    float* Cm  = Bm  + (size_t)NTOK * 16;  // NTOK*16

    hipLaunchKernelGGL(k1a_proj, dim3(NWIN * 4), dim3(256), 0, stream, x, piw, pib, t);
    hipLaunchKernelGGL(k1b_ln,   dim3(NTOK / 4), dim3(256), 0, stream, t, lng, lnb);
    hipLaunchKernelGGL(k2_xz,    dim3(NWIN * 16), dim3(256), 0, stream, t, W_in, cw, cb, xm, szb);
    hipLaunchKernelGGL(k3_dtbc,  dim3(NWIN), dim3(256), 0, stream, xm, wxp, wdt, bdt, dty, Bm, Cm);
    hipLaunchKernelGGL(k4_scan,  dim3(NWIN), dim3(512), 0, stream, xm, dty, Bm, Cm, szb, alog, Dp, dty);
    hipLaunchKernelGGL(k5_wout,  dim3(NWIN * 4), dim3(256), 0, stream, dty, wout, t);
    hipLaunchKernelGGL(k6_out,   dim3(NWIN * 4), dim3(256), 0, stream, t, pow_, pob, x, out);
}

// Round 5
// 391.998 us; speedup vs baseline: 3.6653x; 1.1512x over previous
//
#include <hip/hip_runtime.h>
#include <hip/hip_bf16.h>

// LocalMamba2D: B=8, C=256, H=W=48, win=8 -> 288 windows x 64 tokens.
// D_INNER=512, DSTATE=16, DT_RANK=16, DCONV=4. fp32 I/O; bf16 MFMA GEMMs.

typedef unsigned short u16;
typedef __attribute__((ext_vector_type(8))) unsigned short u16x8;
typedef __attribute__((ext_vector_type(4))) unsigned short u16x4;
typedef __attribute__((ext_vector_type(4))) float f32x4;
typedef __attribute__((ext_vector_type(8))) short s16x8;

#define NTOK 18432
#define NWIN 288

__device__ __forceinline__ float bu2f(u16 u) {
    union { unsigned int i; float f; } v; v.i = ((unsigned int)u) << 16; return v.f;
}
__device__ __forceinline__ u16 f2bu(float f) {
    union { float f; unsigned int i; } v; v.f = f;
    unsigned int i = v.i;
    unsigned int r = (i + 0x7FFFu + ((i >> 16) & 1u)) >> 16;
    return (u16)r;
}
__device__ __forceinline__ float silu(float v) {
    return v * (1.f / (1.f + __expf(-v)));
}
__device__ __forceinline__ s16x8 pack8(f32x4 a, f32x4 b) {
    s16x8 o;
    o[0] = (short)f2bu(a[0]); o[1] = (short)f2bu(a[1]);
    o[2] = (short)f2bu(a[2]); o[3] = (short)f2bu(a[3]);
    o[4] = (short)f2bu(b[0]); o[5] = (short)f2bu(b[1]);
    o[6] = (short)f2bu(b[2]); o[7] = (short)f2bu(b[3]);
    return o;
}

// stage 64 rows x K cols fp32 (row stride ld) -> bf16 LDS rows of (K+8) u16
template<int K>
__device__ __forceinline__ void stage64(const float* __restrict__ src, int ld,
                                        u16* lds, int tid) {
    constexpr int LD = K + 8;
    constexpr int C4 = K / 4;
    for (int i = tid; i < 16 * K; i += 256) {
        int r = i / C4, c = (i % C4) * 4;
        f32x4 v = *(const f32x4*)(src + r * ld + c);
        u16x4 o; o[0] = f2bu(v[0]); o[1] = f2bu(v[1]); o[2] = f2bu(v[2]); o[3] = f2bu(v[3]);
        *(u16x4*)&lds[r * LD + c] = o;
    }
}

// ---------------------------------------------------------------------------
// K1a: proj_in via MFMA. Block = 64 contiguous spatial positions x 64 out ch.
// ---------------------------------------------------------------------------
__global__ __launch_bounds__(256) void k1a_proj(
    const float* __restrict__ x, const float* __restrict__ pw,
    const float* __restrict__ pb, float* __restrict__ xi) {
    __shared__ __attribute__((aligned(16))) u16 a_lds[64 * 264];
    __shared__ __attribute__((aligned(16))) u16 b_lds[64 * 264];
    int tid = threadIdx.x;
    int pt = blockIdx.x >> 2;
    int o0 = (blockIdx.x & 3) * 64;
    int b = pt / 36;
    int hw0 = (pt - b * 36) * 64;

    for (int i = tid; i < 16384; i += 256) {
        int c = i >> 6, pl = i & 63;
        a_lds[pl * 264 + c] = f2bu(x[(b * 256 + c) * 2304 + hw0 + pl]);
    }
    stage64<256>(pw + o0 * 256, 256, b_lds, tid);
    __syncthreads();

    int lane = tid & 63, wv = tid >> 6, fr = lane & 15, fq = lane >> 4;
    f32x4 acc[4] = {};
    {
        const u16* ap = a_lds + (wv * 16 + fr) * 264 + fq * 8;
        const u16* bp = b_lds + fr * 264 + fq * 8;
        for (int kk = 0; kk < 256; kk += 32) {
            s16x8 av = *(const s16x8*)(ap + kk);
#pragma unroll
            for (int nt = 0; nt < 4; nt++) {
                s16x8 bv = *(const s16x8*)(bp + nt * 16 * 264 + kk);
                acc[nt] = __builtin_amdgcn_mfma_f32_16x16x32_bf16(av, bv, acc[nt], 0, 0, 0);
            }
        }
    }
    __syncthreads();
    float* tile = (float*)a_lds;         // 64 x 68
#pragma unroll
    for (int nt = 0; nt < 4; nt++)
#pragma unroll
        for (int r = 0; r < 4; r++)
            tile[(wv * 16 + fq * 4 + r) * 68 + nt * 16 + fr] = acc[nt][r];
    __syncthreads();
    for (int i = tid; i < 4096; i += 256) {
        int pl = i >> 6, oc = i & 63;
        int hw = hw0 + pl;
        int h = hw / 48, w = hw - h * 48;
        int wi = b * 36 + (h >> 3) * 6 + (w >> 3);
        int l = (h & 7) * 8 + (w & 7);
        xi[(wi * 64 + l) * 256 + o0 + oc] = tile[pl * 68 + oc] + pb[o0 + oc];
    }
}

// ---------------------------------------------------------------------------
// K1b: LayerNorm in place on xi (= t). One wave per token.
// ---------------------------------------------------------------------------
__global__ __launch_bounds__(256) void k1b_ln(
    float* __restrict__ t, const float* __restrict__ lg, const float* __restrict__ lb) {
    int tid = threadIdx.x;
    int tok = blockIdx.x * 4 + (tid >> 6);
    int c4 = (tid & 63) * 4;
    f32x4 v = *(const f32x4*)(t + tok * 256 + c4);
    float s = v[0] + v[1] + v[2] + v[3];
    float s2 = v[0]*v[0] + v[1]*v[1] + v[2]*v[2] + v[3]*v[3];
#pragma unroll
    for (int m = 1; m < 64; m <<= 1) {
        s  += __shfl_xor(s, m);
        s2 += __shfl_xor(s2, m);
    }
    float mean = s * (1.f / 256.f);
    float var = s2 * (1.f / 256.f) - mean * mean;
    float rstd = rsqrtf(var + 1e-5f);
    f32x4 g = *(const f32x4*)(lg + c4);
    f32x4 bb = *(const f32x4*)(lb + c4);
    f32x4 o;
#pragma unroll
    for (int j = 0; j < 4; j++) o[j] = (v[j] - mean) * rstd * g[j] + bb[j];
    *(f32x4*)(t + tok * 256 + c4) = o;
}

// ---------------------------------------------------------------------------
// K2: xz = t @ W_in^T via MFMA; e-chunks 0..7 -> conv4+SiLU -> xm,
// chunks 8..15 -> SiLU -> sz. grid NWIN*16, block 256.
// ---------------------------------------------------------------------------
__global__ __launch_bounds__(256) void k2_xz(
    const float* __restrict__ t, const float* __restrict__ W_in,
    const float* __restrict__ conv_w, const float* __restrict__ conv_b,
    float* __restrict__ xm, float* __restrict__ sz) {
    __shared__ __attribute__((aligned(16))) u16 a_lds[64 * 264];
    __shared__ __attribute__((aligned(16))) u16 b_lds[64 * 264];
    int tid = threadIdx.x;
    int wi = blockIdx.x >> 4;
    int e0 = (blockIdx.x & 15) * 64;

    stage64<256>(t + wi * 16384, 256, a_lds, tid);
    stage64<256>(W_in + e0 * 256, 256, b_lds, tid);
    __syncthreads();

    int lane = tid & 63, wv = tid >> 6, fr = lane & 15, fq = lane >> 4;
    f32x4 acc[4] = {};
    {
        const u16* ap = a_lds + (wv * 16 + fr) * 264 + fq * 8;
        const u16* bp = b_lds + fr * 264 + fq * 8;
        for (int kk = 0; kk < 256; kk += 32) {
            s16x8 av = *(const s16x8*)(ap + kk);
#pragma unroll
            for (int nt = 0; nt < 4; nt++) {
                s16x8 bv = *(const s16x8*)(bp + nt * 16 * 264 + kk);
                acc[nt] = __builtin_amdgcn_mfma_f32_16x16x32_bf16(av, bv, acc[nt], 0, 0, 0);
            }
        }
    }

    if (e0 < 512) {
        __syncthreads();
        float* raw = (float*)a_lds;      // 64 x 68
#pragma unroll
        for (int nt = 0; nt < 4; nt++)
#pragma unroll
            for (int r = 0; r < 4; r++)
                raw[(wv * 16 + fq * 4 + r) * 68 + nt * 16 + fr] = acc[nt][r];
        __syncthreads();
        int dl = tid & 63;
        int d = e0 + dl;
        f32x4 cw4 = *(const f32x4*)(conv_w + d * 4);
        float cbv = conv_b[d];
#pragma unroll
        for (int it = 0; it < 16; it++) {
            int l = (tid >> 6) + it * 4;
            float v = cbv + raw[l * 68 + dl] * cw4[3];
            if (l >= 1) v += raw[(l - 1) * 68 + dl] * cw4[2];
            if (l >= 2) v += raw[(l - 2) * 68 + dl] * cw4[1];
            if (l >= 3) v += raw[(l - 3) * 68 + dl] * cw4[0];
            xm[(wi * 64 + l) * 512 + d] = silu(v);
        }
    } else {
        int z0 = e0 - 512;
#pragma unroll
        for (int nt = 0; nt < 4; nt++)
#pragma unroll
            for (int r = 0; r < 4; r++) {
                int l = wv * 16 + fq * 4 + r;
                sz[(wi * 64 + l) * 512 + z0 + nt * 16 + fr] = silu(acc[nt][r]);
            }
    }
}

// ---------------------------------------------------------------------------
// K3a: xdb[NTOK x 48] = xm @ W_xproj^T, flat over tokens. M=16 per block,
// 4 waves split K=512 into 128 each; LDS partial reduction.
// cols 0..15 -> xdb (bf16 scratch), 16..31 -> Bm, 32..47 -> Cm.
// grid NTOK/16 = 1152, block 256.
// ---------------------------------------------------------------------------
__global__ __launch_bounds__(256) void k3a_xdb(
    const float* __restrict__ xm, const float* __restrict__ W_xproj,
    u16* __restrict__ xdb, float* __restrict__ Bm, float* __restrict__ Cm) {
    __shared__ float part[4 * 768];      // 12 KB
    int tid = threadIdx.x;
    int tok0 = blockIdx.x * 16;
    int lane = tid & 63, w = tid >> 6;
    int fr = lane & 15, fq = lane >> 4;
    int k0 = w * 128;

    f32x4 acc[3] = {};
    const float* ap = xm + (size_t)(tok0 + fr) * 512 + k0 + fq * 8;
    const float* bp = W_xproj + (size_t)fr * 512 + k0 + fq * 8;
#pragma unroll
    for (int kk = 0; kk < 128; kk += 32) {
        f32x4 a0 = *(const f32x4*)(ap + kk);
        f32x4 a1 = *(const f32x4*)(ap + kk + 4);
        s16x8 av = pack8(a0, a1);
#pragma unroll
        for (int nt = 0; nt < 3; nt++) {
            f32x4 b0 = *(const f32x4*)(bp + nt * 16 * 512 + kk);
            f32x4 b1 = *(const f32x4*)(bp + nt * 16 * 512 + kk + 4);
            acc[nt] = __builtin_amdgcn_mfma_f32_16x16x32_bf16(av, pack8(b0, b1), acc[nt], 0, 0, 0);
        }
    }
#pragma unroll
    for (int nt = 0; nt < 3; nt++)
#pragma unroll
        for (int r = 0; r < 4; r++)
            part[w * 768 + (fq * 4 + r) * 48 + nt * 16 + fr] = acc[nt][r];
    __syncthreads();
    for (int i = tid; i < 768; i += 256) {
        float v = part[i] + part[768 + i] + part[1536 + i] + part[2304 + i];
        int row = i / 48, col = i - row * 48;
        int tok = tok0 + row;
        if (col < 16)      xdb[(size_t)tok * 16 + col] = f2bu(v);
        else if (col < 32) Bm[(size_t)tok * 16 + col - 16] = v;
        else               Cm[(size_t)tok * 16 + col - 32] = v;
    }
}

// ---------------------------------------------------------------------------
// K3b: dt[NTOK x 512] = softplus(xdb[:, :16] @ W_dt^T + b_dt). K=16 padded
// to 32 with zeros (fq>=2 lanes contribute 0). M=16/block, wave = 8 N-tiles.
// grid NTOK/16 = 1152, block 256.
// ---------------------------------------------------------------------------
__global__ __launch_bounds__(256) void k3b_dt(
    const u16* __restrict__ xdb, const float* __restrict__ W_dt,
    const float* __restrict__ b_dt, float* __restrict__ dt) {
    int tid = threadIdx.x;
    int tok0 = blockIdx.x * 16;
    int lane = tid & 63, w = tid >> 6;
    int fr = lane & 15, fq = lane >> 4;

    s16x8 av = {};
    if (fq < 2)
        av = *(const s16x8*)(xdb + (size_t)(tok0 + fr) * 16 + fq * 8);
    f32x4 acc[8] = {};
#pragma unroll
    for (int j = 0; j < 8; j++) {
        s16x8 bv = {};
        if (fq < 2) {
            int d = (w * 8 + j) * 16 + fr;
            f32x4 b0 = *(const f32x4*)(W_dt + d * 16 + fq * 8);
            f32x4 b1 = *(const f32x4*)(W_dt + d * 16 + fq * 8 + 4);
            bv = pack8(b0, b1);
        }
        acc[j] = __builtin_amdgcn_mfma_f32_16x16x32_bf16(av, bv, acc[j], 0, 0, 0);
    }
#pragma unroll
    for (int j = 0; j < 8; j++) {
        int d = (w * 8 + j) * 16 + fr;
        float bdv = b_dt[d];
#pragma unroll
        for (int r = 0; r < 4; r++) {
            float s = acc[j][r] + bdv;
            float sp = (s > 20.f) ? s : __logf(1.f + __expf(s));
            dt[(size_t)(tok0 + fq * 4 + r) * 512 + d] = sp;
        }
    }
}

// ---------------------------------------------------------------------------
// K4: selective scan. One block per window, one thread per d.
// ---------------------------------------------------------------------------
__global__ __launch_bounds__(512) void k4_scan(
    const float* __restrict__ xm, const float* dt_in,
    const float* __restrict__ Bm, const float* __restrict__ Cm,
    const float* __restrict__ sz, const float* __restrict__ A_log,
    const float* __restrict__ Dp, float* y) {
    int wi = blockIdx.x, d = threadIdx.x;
    __shared__ float lB[1024], lC[1024];
#pragma unroll
    for (int q = 0; q < 2; q++) {
        int i = d + q * 512;
        lB[i] = Bm[wi * 1024 + i];
        lC[i] = Cm[wi * 1024 + i];
    }
    float A[16];
#pragma unroll
    for (int n = 0; n < 16; n++) A[n] = -__expf(A_log[d * 16 + n]);
    float Dd = Dp[d];
    float h[16];
#pragma unroll
    for (int n = 0; n < 16; n++) h[n] = 0.f;
    __syncthreads();
#pragma unroll 1
    for (int l = 0; l < 64; l++) {
        int idx = (wi * 64 + l) * 512 + d;
        float dtv = dt_in[idx];
        float xv  = xm[idx];
        float szv = sz[idx];
        float dx = dtv * xv;
        float yv = 0.f;
#pragma unroll
        for (int n = 0; n < 16; n++) {
            float dA = __expf(dtv * A[n]);
            h[n] = dA * h[n] + dx * lB[l * 16 + n];
            yv += h[n] * lC[l * 16 + n];
        }
        y[idx] = (yv + xv * Dd) * szv;
    }
}

// ---------------------------------------------------------------------------
// K5: ytok = y @ W_out^T via MFMA (K=512). grid NWIN*4, block 256.
// ---------------------------------------------------------------------------
__global__ __launch_bounds__(256) void k5_wout(
    const float* __restrict__ y, const float* __restrict__ W_out,
    float* __restrict__ ytok) {
    __shared__ __attribute__((aligned(16))) u16 a_lds[64 * 520];
    __shared__ __attribute__((aligned(16))) u16 b_lds[64 * 520];
    int tid = threadIdx.x;
    int wi = blockIdx.x >> 2;
    int o0 = (blockIdx.x & 3) * 64;

    stage64<512>(y + wi * 32768, 512, a_lds, tid);
    stage64<512>(W_out + o0 * 512, 512, b_lds, tid);
    __syncthreads();

    int lane = tid & 63, wv = tid >> 6, fr = lane & 15, fq = lane >> 4;
    f32x4 acc[4] = {};
    {
        const u16* ap = a_lds + (wv * 16 + fr) * 520 + fq * 8;
        const u16* bp = b_lds + fr * 520 + fq * 8;
        for (int kk = 0; kk < 512; kk += 32) {
            s16x8 av = *(const s16x8*)(ap + kk);
#pragma unroll
            for (int nt = 0; nt < 4; nt++) {
                s16x8 bv = *(const s16x8*)(bp + nt * 16 * 520 + kk);
                acc[nt] = __builtin_amdgcn_mfma_f32_16x16x32_bf16(av, bv, acc[nt], 0, 0, 0);
            }
        }
    }
#pragma unroll
    for (int nt = 0; nt < 4; nt++)
#pragma unroll
        for (int r = 0; r < 4; r++) {
            int l = wv * 16 + fq * 4 + r;
            ytok[(wi * 64 + l) * 256 + o0 + nt * 16 + fr] = acc[nt][r];
        }
}

// ---------------------------------------------------------------------------
// K6: out = ytok @ proj_out_w^T + b + residual, window-merged. grid NWIN*4.
// ---------------------------------------------------------------------------
__global__ __launch_bounds__(256) void k6_out(
    const float* __restrict__ ytok, const float* __restrict__ pw,
    const float* __restrict__ pb, const float* __restrict__ xres,
    float* __restrict__ out) {
    __shared__ __attribute__((aligned(16))) u16 a_lds[64 * 264];
    __shared__ __attribute__((aligned(16))) u16 b_lds[64 * 264];
    int tid = threadIdx.x;
    int wi = blockIdx.x >> 2;
    int o0 = (blockIdx.x & 3) * 64;

    stage64<256>(ytok + wi * 16384, 256, a_lds, tid);
    stage64<256>(pw + o0 * 256, 256, b_lds, tid);
    __syncthreads();

    int lane = tid & 63, wv = tid >> 6, fr = lane & 15, fq = lane >> 4;
    f32x4 acc[4] = {};
    {
        const u16* ap = a_lds + (wv * 16 + fr) * 264 + fq * 8;
        const u16* bp = b_lds + fr * 264 + fq * 8;
        for (int kk = 0; kk < 256; kk += 32) {
            s16x8 av = *(const s16x8*)(ap + kk);
#pragma unroll
            for (int nt = 0; nt < 4; nt++) {
                s16x8 bv = *(const s16x8*)(bp + nt * 16 * 264 + kk);
                acc[nt] = __builtin_amdgcn_mfma_f32_16x16x32_bf16(av, bv, acc[nt], 0, 0, 0);
            }
        }
    }
    __syncthreads();
    float* tile = (float*)a_lds;         // 64 x 68
#pragma unroll
    for (int nt = 0; nt < 4; nt++)
#pragma unroll
        for (int r = 0; r < 4; r++)
            tile[(wv * 16 + fq * 4 + r) * 68 + nt * 16 + fr] = acc[nt][r];
    __syncthreads();

    int b = wi / 36; int rem = wi - b * 36; int ih = rem / 6; int iw = rem - ih * 6;
    for (int i = tid; i < 4096; i += 256) {
        int oc = i >> 6, l = i & 63;
        int h = ih * 8 + (l >> 3), w = iw * 8 + (l & 7);
        int o = o0 + oc;
        int gidx = ((b * 256 + o) * 48 + h) * 48 + w;
        out[gidx] = tile[l * 68 + oc] + pb[o] + xres[gidx];
    }
}

// ---------------------------------------------------------------------------
extern "C" void kernel_launch(void* const* d_in, const int* in_sizes, int n_in,
                              void* d_out, int out_size, void* d_ws, size_t ws_size,
                              hipStream_t stream) {
    (void)in_sizes; (void)n_in; (void)out_size; (void)ws_size;
    const float* x    = (const float*)d_in[0];
    const float* piw  = (const float*)d_in[1];
    const float* pib  = (const float*)d_in[2];
    const float* lng  = (const float*)d_in[3];
    const float* lnb  = (const float*)d_in[4];
    const float* W_in = (const float*)d_in[5];
    const float* cw   = (const float*)d_in[6];
    const float* cb   = (const float*)d_in[7];
    const float* wxp  = (const float*)d_in[8];
    const float* wdt  = (const float*)d_in[9];
    const float* bdt  = (const float*)d_in[10];
    const float* alog = (const float*)d_in[11];
    const float* Dp   = (const float*)d_in[12];
    const float* wout = (const float*)d_in[13];
    const float* pow_ = (const float*)d_in[14];
    const float* pob  = (const float*)d_in[15];
    float* out = (float*)d_out;

    float* ws  = (float*)d_ws;
    float* t   = ws;                       // NTOK*256 (xi -> t; xdb scratch; ytok after K5)
    float* xm  = t   + (size_t)NTOK * 256; // NTOK*512
    float* szb = xm  + (size_t)NTOK * 512; // NTOK*512
    float* dty = szb + (size_t)NTOK * 512; // NTOK*512 (dt, overwritten by y in K4)
    float* Bm  = dty + (size_t)NTOK * 512; // NTOK*16
    float* Cm  = Bm  + (size_t)NTOK * 16;  // NTOK*16
    u16*   xdb = (u16*)t;                  // NTOK*16 u16 (t is dead between K2 and K5)

    hipLaunchKernelGGL(k1a_proj, dim3(NWIN * 4), dim3(256), 0, stream, x, piw, pib, t);
    hipLaunchKernelGGL(k1b_ln,   dim3(NTOK / 4), dim3(256), 0, stream, t, lng, lnb);
    hipLaunchKernelGGL(k2_xz,    dim3(NWIN * 16), dim3(256), 0, stream, t, W_in, cw, cb, xm, szb);
    hipLaunchKernelGGL(k3a_xdb,  dim3(NTOK / 16), dim3(256), 0, stream, xm, wxp, xdb, Bm, Cm);
    hipLaunchKernelGGL(k3b_dt,   dim3(NTOK / 16), dim3(256), 0, stream, xdb, wdt, bdt, dty);
    hipLaunchKernelGGL(k4_scan,  dim3(NWIN), dim3(512), 0, stream, xm, dty, Bm, Cm, szb, alog, Dp, dty);
    hipLaunchKernelGGL(k5_wout,  dim3(NWIN * 4), dim3(256), 0, stream, dty, wout, t);
    hipLaunchKernelGGL(k6_out,   dim3(NWIN * 4), dim3(256), 0, stream, t, pow_, pob, x, out);
}

// Round 6
// 205.608 us; speedup vs baseline: 6.9881x; 1.9065x over previous
//
#include <hip/hip_runtime.h>
#include <hip/hip_bf16.h>

// LocalMamba2D: B=8, C=256, H=W=48, win=8 -> 288 windows x 64 tokens.
// D_INNER=512, DSTATE=16, DT_RANK=16, DCONV=4. fp32 I/O.
// bf16 operand buffers materialized once; all big GEMMs are 128x128 MFMA tiles.

typedef unsigned short u16;
typedef __attribute__((ext_vector_type(8))) unsigned short u16x8;
typedef __attribute__((ext_vector_type(4))) unsigned short u16x4;
typedef __attribute__((ext_vector_type(4))) float f32x4;
typedef __attribute__((ext_vector_type(8))) short s16x8;

#define NTOK 18432
#define NWIN 288

__device__ __forceinline__ float bu2f(u16 u) {
    union { unsigned int i; float f; } v; v.i = ((unsigned int)u) << 16; return v.f;
}
__device__ __forceinline__ u16 f2bu(float f) {
    union { float f; unsigned int i; } v; v.f = f;
    unsigned int i = v.i;
    unsigned int r = (i + 0x7FFFu + ((i >> 16) & 1u)) >> 16;
    return (u16)r;
}
__device__ __forceinline__ float silu(float v) {
    return v * (1.f / (1.f + __expf(-v)));
}

// ---------------------------------------------------------------------------
// K0: convert weights to bf16 once. dst layout: wib|wob|piwb|powb|wxb
// ---------------------------------------------------------------------------
__global__ __launch_bounds__(256) void k0_w2b(
    const float* __restrict__ wi, const float* __restrict__ wo,
    const float* __restrict__ pi, const float* __restrict__ po,
    const float* __restrict__ wx, u16* __restrict__ dst) {
    int g0 = blockIdx.x * 256 + threadIdx.x;
    for (int g = g0; g < 137216; g += gridDim.x * 256) {
        int e = g * 4;
        const float* s;
        if (e < 262144)      s = wi + e;
        else if (e < 393216) s = wo + (e - 262144);
        else if (e < 458752) s = pi + (e - 393216);
        else if (e < 524288) s = po + (e - 458752);
        else                 s = wx + (e - 524288);
        f32x4 v = *(const f32x4*)s;
        u16x4 o; o[0] = f2bu(v[0]); o[1] = f2bu(v[1]); o[2] = f2bu(v[2]); o[3] = f2bu(v[3]);
        *(u16x4*)(dst + e) = o;
    }
}

// ---------------------------------------------------------------------------
// Generic 128x128 bf16 MFMA tile: A[M][KT] row-major, B[N][KT] row-major.
// 256 threads = 4 waves in 2x2; each wave 64x64 (acc[4][4] f32x4).
// ---------------------------------------------------------------------------
template<int KTOT>
__device__ __forceinline__ void gemm128(
    const u16* __restrict__ A, const u16* __restrict__ B,
    int tok0, int n0, u16* a_lds, u16* b_lds, f32x4 (&acc)[4][4], int tid) {
    int lane = tid & 63, wv = tid >> 6;
    int fr = lane & 15, fq = lane >> 4;
    int wr = wv >> 1, wc = wv & 1;
#pragma unroll 1
    for (int ks = 0; ks < KTOT / 64; ks++) {
        if (ks) __syncthreads();
        int k0 = ks * 64;
#pragma unroll
        for (int p = 0; p < 4; p++) {
            int c = tid + p * 256;        // 0..1023
            int r = c >> 3, c8 = c & 7;
            *(u16x8*)&a_lds[r * 72 + c8 * 8] =
                *(const u16x8*)(A + (size_t)(tok0 + r) * KTOT + k0 + c8 * 8);
            *(u16x8*)&b_lds[r * 72 + c8 * 8] =
                *(const u16x8*)(B + (size_t)(n0 + r) * KTOT + k0 + c8 * 8);
        }
        __syncthreads();
        const u16* ap = a_lds + (wr * 64 + fr) * 72 + fq * 8;
        const u16* bp = b_lds + (wc * 64 + fr) * 72 + fq * 8;
#pragma unroll
        for (int kk = 0; kk < 2; kk++) {
            s16x8 av[4], bv[4];
#pragma unroll
            for (int m = 0; m < 4; m++) av[m] = *(const s16x8*)(ap + m * 16 * 72 + kk * 32);
#pragma unroll
            for (int n = 0; n < 4; n++) bv[n] = *(const s16x8*)(bp + n * 16 * 72 + kk * 32);
#pragma unroll
            for (int m = 0; m < 4; m++)
#pragma unroll
                for (int n = 0; n < 4; n++)
                    acc[m][n] = __builtin_amdgcn_mfma_f32_16x16x32_bf16(av[m], bv[n], acc[m][n], 0, 0, 0);
        }
    }
}

// ---------------------------------------------------------------------------
// K1a: proj_in via MFMA (gather prologue; B from piwb). Writes xi fp32 + bias.
// ---------------------------------------------------------------------------
__global__ __launch_bounds__(256) void k1a_proj(
    const float* __restrict__ x, const u16* __restrict__ piwb,
    const float* __restrict__ pb, float* __restrict__ xi) {
    __shared__ __attribute__((aligned(16))) u16 a_lds[64 * 264];
    __shared__ __attribute__((aligned(16))) u16 b_lds[64 * 264];
    int tid = threadIdx.x;
    int pt = blockIdx.x >> 2;
    int o0 = (blockIdx.x & 3) * 64;
    int b = pt / 36;
    int hw0 = (pt - b * 36) * 64;

    for (int i = tid; i < 16384; i += 256) {
        int c = i >> 6, pl = i & 63;
        a_lds[pl * 264 + c] = f2bu(x[(b * 256 + c) * 2304 + hw0 + pl]);
    }
    for (int i = tid; i < 2048; i += 256) {
        int r = i >> 5, c8 = i & 31;
        *(u16x8*)&b_lds[r * 264 + c8 * 8] = *(const u16x8*)(piwb + (o0 + r) * 256 + c8 * 8);
    }
    __syncthreads();

    int lane = tid & 63, wv = tid >> 6, fr = lane & 15, fq = lane >> 4;
    f32x4 acc[4] = {};
    {
        const u16* ap = a_lds + (wv * 16 + fr) * 264 + fq * 8;
        const u16* bp = b_lds + fr * 264 + fq * 8;
        for (int kk = 0; kk < 256; kk += 32) {
            s16x8 av = *(const s16x8*)(ap + kk);
#pragma unroll
            for (int nt = 0; nt < 4; nt++) {
                s16x8 bv = *(const s16x8*)(bp + nt * 16 * 264 + kk);
                acc[nt] = __builtin_amdgcn_mfma_f32_16x16x32_bf16(av, bv, acc[nt], 0, 0, 0);
            }
        }
    }
    __syncthreads();
    float* tile = (float*)a_lds;         // 64 x 68
#pragma unroll
    for (int nt = 0; nt < 4; nt++)
#pragma unroll
        for (int r = 0; r < 4; r++)
            tile[(wv * 16 + fq * 4 + r) * 68 + nt * 16 + fr] = acc[nt][r];
    __syncthreads();
    for (int i = tid; i < 4096; i += 256) {
        int pl = i >> 6, oc = i & 63;
        int hw = hw0 + pl;
        int h = hw / 48, w = hw - h * 48;
        int wi = b * 36 + (h >> 3) * 6 + (w >> 3);
        int l = (h & 7) * 8 + (w & 7);
        xi[(wi * 64 + l) * 256 + o0 + oc] = tile[pl * 68 + oc] + pb[o0 + oc];
    }
}

// ---------------------------------------------------------------------------
// K1b: LayerNorm, reads xi fp32, writes t_bf bf16. One wave per token.
// ---------------------------------------------------------------------------
__global__ __launch_bounds__(256) void k1b_ln(
    const float* __restrict__ xi, const float* __restrict__ lg,
    const float* __restrict__ lb, u16* __restrict__ t_bf) {
    int tid = threadIdx.x;
    int tok = blockIdx.x * 4 + (tid >> 6);
    int c4 = (tid & 63) * 4;
    f32x4 v = *(const f32x4*)(xi + tok * 256 + c4);
    float s = v[0] + v[1] + v[2] + v[3];
    float s2 = v[0]*v[0] + v[1]*v[1] + v[2]*v[2] + v[3]*v[3];
#pragma unroll
    for (int m = 1; m < 64; m <<= 1) {
        s  += __shfl_xor(s, m);
        s2 += __shfl_xor(s2, m);
    }
    float mean = s * (1.f / 256.f);
    float var = s2 * (1.f / 256.f) - mean * mean;
    float rstd = rsqrtf(var + 1e-5f);
    f32x4 g = *(const f32x4*)(lg + c4);
    f32x4 bb = *(const f32x4*)(lb + c4);
    u16x4 o;
#pragma unroll
    for (int j = 0; j < 4; j++) o[j] = f2bu((v[j] - mean) * rstd * g[j] + bb[j]);
    *(u16x4*)(t_bf + tok * 256 + c4) = o;
}

// ---------------------------------------------------------------------------
// K2: xz = t_bf @ W_in^T flat GEMM (M=18432,N=1024,K=256), 128x128 tiles.
// n0<512: conv4+SiLU -> xm_bf (LDS bounce, tile = 2 windows); else SiLU -> sz_bf.
// grid 144*8, block 256.
// ---------------------------------------------------------------------------
__global__ __launch_bounds__(256) void k2_gemm(
    const u16* __restrict__ t_bf, const u16* __restrict__ wib,
    const float* __restrict__ cw, const float* __restrict__ cb,
    u16* __restrict__ xm_bf, u16* __restrict__ sz_bf) {
    __shared__ __attribute__((aligned(16))) char smem[36864];
    u16* a_lds = (u16*)smem;
    u16* b_lds = a_lds + 128 * 72;
    float* epi = (float*)smem;           // 128 x 68 (reuse after compute)
    int tid = threadIdx.x;
    int bm = blockIdx.x >> 3, bn = blockIdx.x & 7;
    int tok0 = bm * 128, n0 = bn * 128;

    f32x4 acc[4][4] = {};
    gemm128<256>(t_bf, wib, tok0, n0, a_lds, b_lds, acc, tid);

    int lane = tid & 63, wv = tid >> 6, fr = lane & 15, fq = lane >> 4;
    int wr = wv >> 1, wc = wv & 1;

    if (n0 >= 512) {
        int z0 = n0 - 512;
#pragma unroll
        for (int m = 0; m < 4; m++)
#pragma unroll
            for (int n = 0; n < 4; n++)
#pragma unroll
                for (int r = 0; r < 4; r++) {
                    int tok = tok0 + wr * 64 + m * 16 + fq * 4 + r;
                    sz_bf[(size_t)tok * 512 + z0 + wc * 64 + n * 16 + fr] =
                        f2bu(silu(acc[m][n][r]));
                }
    } else {
        __syncthreads();
#pragma unroll 1
        for (int p = 0; p < 2; p++) {
            if (p) __syncthreads();
            if (wc == p) {
#pragma unroll
                for (int m = 0; m < 4; m++)
#pragma unroll
                    for (int n = 0; n < 4; n++)
#pragma unroll
                        for (int r = 0; r < 4; r++)
                            epi[(wr * 64 + m * 16 + fq * 4 + r) * 68 + n * 16 + fr] = acc[m][n][r];
            }
            __syncthreads();
            int col = tid & 63;
            int d = n0 + p * 64 + col;
            f32x4 cw4 = *(const f32x4*)(cw + d * 4);
            float cbv = cb[d];
            int r0 = (tid >> 6) * 32;
#pragma unroll 4
            for (int g = 0; g < 32; g++) {
                int l = r0 + g, lw = l & 63;
                float v = cbv + epi[l * 68 + col] * cw4[3];
                if (lw >= 1) v += epi[(l - 1) * 68 + col] * cw4[2];
                if (lw >= 2) v += epi[(l - 2) * 68 + col] * cw4[1];
                if (lw >= 3) v += epi[(l - 3) * 68 + col] * cw4[0];
                xm_bf[(size_t)(tok0 + l) * 512 + d] = f2bu(silu(v));
            }
        }
    }
}

// ---------------------------------------------------------------------------
// K3a: xdb[NTOK x 48] = xm_bf @ W_xproj^T. M=16/block, 4 waves split K=512.
// cols 0..15 -> xdb bf16, 16..31 -> Bm, 32..47 -> Cm. grid 1152.
// ---------------------------------------------------------------------------
__global__ __launch_bounds__(256) void k3a_xdb(
    const u16* __restrict__ xm_bf, const u16* __restrict__ wxb,
    u16* __restrict__ xdb, float* __restrict__ Bm, float* __restrict__ Cm) {
    __shared__ float part[4 * 768];
    int tid = threadIdx.x;
    int tok0 = blockIdx.x * 16;
    int lane = tid & 63, w = tid >> 6;
    int fr = lane & 15, fq = lane >> 4;
    int k0 = w * 128;

    f32x4 acc[3] = {};
    const u16* ap = xm_bf + (size_t)(tok0 + fr) * 512 + k0 + fq * 8;
    const u16* bp = wxb + (size_t)fr * 512 + k0 + fq * 8;
#pragma unroll
    for (int kk = 0; kk < 128; kk += 32) {
        s16x8 av = *(const s16x8*)(ap + kk);
#pragma unroll
        for (int nt = 0; nt < 3; nt++) {
            s16x8 bv = *(const s16x8*)(bp + nt * 16 * 512 + kk);
            acc[nt] = __builtin_amdgcn_mfma_f32_16x16x32_bf16(av, bv, acc[nt], 0, 0, 0);
        }
    }
#pragma unroll
    for (int nt = 0; nt < 3; nt++)
#pragma unroll
        for (int r = 0; r < 4; r++)
            part[w * 768 + (fq * 4 + r) * 48 + nt * 16 + fr] = acc[nt][r];
    __syncthreads();
    for (int i = tid; i < 768; i += 256) {
        float v = part[i] + part[768 + i] + part[1536 + i] + part[2304 + i];
        int row = i / 48, col = i - row * 48;
        int tok = tok0 + row;
        if (col < 16)      xdb[(size_t)tok * 16 + col] = f2bu(v);
        else if (col < 32) Bm[(size_t)tok * 16 + col - 16] = v;
        else               Cm[(size_t)tok * 16 + col - 32] = v;
    }
}

// ---------------------------------------------------------------------------
// K3b: dt = softplus(xdb @ W_dt^T + b_dt), K=16 padded to 32. grid 1152.
// ---------------------------------------------------------------------------
__global__ __launch_bounds__(256) void k3b_dt(
    const u16* __restrict__ xdb, const float* __restrict__ W_dt,
    const float* __restrict__ b_dt, float* __restrict__ dt) {
    int tid = threadIdx.x;
    int tok0 = blockIdx.x * 16;
    int lane = tid & 63, w = tid >> 6;
    int fr = lane & 15, fq = lane >> 4;

    s16x8 av = {};
    if (fq < 2)
        av = *(const s16x8*)(xdb + (size_t)(tok0 + fr) * 16 + fq * 8);
    f32x4 acc[8] = {};
#pragma unroll
    for (int j = 0; j < 8; j++) {
        s16x8 bv = {};
        if (fq < 2) {
            int d = (w * 8 + j) * 16 + fr;
            f32x4 b0 = *(const f32x4*)(W_dt + d * 16 + fq * 8);
            f32x4 b1 = *(const f32x4*)(W_dt + d * 16 + fq * 8 + 4);
            bv[0] = (short)f2bu(b0[0]); bv[1] = (short)f2bu(b0[1]);
            bv[2] = (short)f2bu(b0[2]); bv[3] = (short)f2bu(b0[3]);
            bv[4] = (short)f2bu(b1[0]); bv[5] = (short)f2bu(b1[1]);
            bv[6] = (short)f2bu(b1[2]); bv[7] = (short)f2bu(b1[3]);
        }
        acc[j] = __builtin_amdgcn_mfma_f32_16x16x32_bf16(av, bv, acc[j], 0, 0, 0);
    }
#pragma unroll
    for (int j = 0; j < 8; j++) {
        int d = (w * 8 + j) * 16 + fr;
        float bdv = b_dt[d];
#pragma unroll
        for (int r = 0; r < 4; r++) {
            float s = acc[j][r] + bdv;
            float sp = (s > 20.f) ? s : __logf(1.f + __expf(s));
            dt[(size_t)(tok0 + fq * 4 + r) * 512 + d] = sp;
        }
    }
}

// ---------------------------------------------------------------------------
// K4: selective scan. One block per window, one thread per d. bf16 in/out.
// ---------------------------------------------------------------------------
__global__ __launch_bounds__(512) void k4_scan(
    const u16* __restrict__ xm_bf, const float* __restrict__ dt_in,
    const float* __restrict__ Bm, const float* __restrict__ Cm,
    const u16* __restrict__ sz_bf, const float* __restrict__ A_log,
    const float* __restrict__ Dp, u16* __restrict__ y_bf) {
    int wi = blockIdx.x, d = threadIdx.x;
    __shared__ float lB[1024], lC[1024];
#pragma unroll
    for (int q = 0; q < 2; q++) {
        int i = d + q * 512;
        lB[i] = Bm[wi * 1024 + i];
        lC[i] = Cm[wi * 1024 + i];
    }
    float A[16];
#pragma unroll
    for (int n = 0; n < 16; n++) A[n] = -__expf(A_log[d * 16 + n]);
    float Dd = Dp[d];
    float h[16];
#pragma unroll
    for (int n = 0; n < 16; n++) h[n] = 0.f;
    __syncthreads();
#pragma unroll 1
    for (int l = 0; l < 64; l++) {
        int idx = (wi * 64 + l) * 512 + d;
        float dtv = dt_in[idx];
        float xv  = bu2f(xm_bf[idx]);
        float szv = bu2f(sz_bf[idx]);
        float dx = dtv * xv;
        float yv = 0.f;
#pragma unroll
        for (int n = 0; n < 16; n++) {
            float dA = __expf(dtv * A[n]);
            h[n] = dA * h[n] + dx * lB[l * 16 + n];
            yv += h[n] * lC[l * 16 + n];
        }
        y_bf[idx] = f2bu((yv + xv * Dd) * szv);
    }
}

// ---------------------------------------------------------------------------
// K5: ytok_bf = y_bf @ W_out^T (M=18432,N=256,K=512), 128x128. grid 144*2.
// ---------------------------------------------------------------------------
__global__ __launch_bounds__(256) void k5_gemm(
    const u16* __restrict__ y_bf, const u16* __restrict__ wob,
    u16* __restrict__ ytok_bf) {
    __shared__ __attribute__((aligned(16))) char smem[36864];
    u16* a_lds = (u16*)smem;
    u16* b_lds = a_lds + 128 * 72;
    int tid = threadIdx.x;
    int bm = blockIdx.x >> 1, bn = blockIdx.x & 1;
    int tok0 = bm * 128, n0 = bn * 128;

    f32x4 acc[4][4] = {};
    gemm128<512>(y_bf, wob, tok0, n0, a_lds, b_lds, acc, tid);

    int lane = tid & 63, wv = tid >> 6, fr = lane & 15, fq = lane >> 4;
    int wr = wv >> 1, wc = wv & 1;
#pragma unroll
    for (int m = 0; m < 4; m++)
#pragma unroll
        for (int n = 0; n < 4; n++)
#pragma unroll
            for (int r = 0; r < 4; r++) {
                int tok = tok0 + wr * 64 + m * 16 + fq * 4 + r;
                ytok_bf[(size_t)tok * 256 + n0 + wc * 64 + n * 16 + fr] =
                    f2bu(acc[m][n][r]);
            }
}

// ---------------------------------------------------------------------------
// K6: out = ytok_bf @ proj_out^T + pb + residual, window-merge scatter.
// (M=18432,N=256,K=256), 128x128. grid 144*2.
// ---------------------------------------------------------------------------
__global__ __launch_bounds__(256) void k6_gemm(
    const u16* __restrict__ ytok_bf, const u16* __restrict__ powb,
    const float* __restrict__ pob, const float* __restrict__ xres,
    float* __restrict__ out) {
    __shared__ __attribute__((aligned(16))) char smem[36864];
    u16* a_lds = (u16*)smem;
    u16* b_lds = a_lds + 128 * 72;
    float* epi = (float*)smem;           // 128 x 68
    int tid = threadIdx.x;
    int bm = blockIdx.x >> 1, bn = blockIdx.x & 1;
    int tok0 = bm * 128, n0 = bn * 128;

    f32x4 acc[4][4] = {};
    gemm128<256>(ytok_bf, powb, tok0, n0, a_lds, b_lds, acc, tid);

    int lane = tid & 63, wv = tid >> 6, fr = lane & 15, fq = lane >> 4;
    int wr = wv >> 1, wc = wv & 1;
    __syncthreads();
#pragma unroll 1
    for (int p = 0; p < 2; p++) {
        if (p) __syncthreads();
        if (wc == p) {
#pragma unroll
            for (int m = 0; m < 4; m++)
#pragma unroll
                for (int n = 0; n < 4; n++)
#pragma unroll
                    for (int r = 0; r < 4; r++)
                        epi[(wr * 64 + m * 16 + fq * 4 + r) * 68 + n * 16 + fr] = acc[m][n][r];
        }
        __syncthreads();
        for (int i = tid; i < 8192; i += 256) {
            int row = i & 127, oc = i >> 7;
            int tok = tok0 + row;
            int wi = tok >> 6, l = tok & 63;
            int b = wi / 36; int rem = wi - b * 36; int ih = rem / 6; int iw = rem - ih * 6;
            int h = ih * 8 + (l >> 3), w = iw * 8 + (l & 7);
            int o = n0 + p * 64 + oc;
            int gidx = ((b * 256 + o) * 48 + h) * 48 + w;
            out[gidx] = epi[row * 68 + oc] + pob[o] + xres[gidx];
        }
    }
}

// ---------------------------------------------------------------------------
extern "C" void kernel_launch(void* const* d_in, const int* in_sizes, int n_in,
                              void* d_out, int out_size, void* d_ws, size_t ws_size,
                              hipStream_t stream) {
    (void)in_sizes; (void)n_in; (void)out_size; (void)ws_size;
    const float* x    = (const float*)d_in[0];
    const float* piw  = (const float*)d_in[1];
    const float* pib  = (const float*)d_in[2];
    const float* lng  = (const float*)d_in[3];
    const float* lnb  = (const float*)d_in[4];
    const float* W_in = (const float*)d_in[5];
    const float* cw   = (const float*)d_in[6];
    const float* cb   = (const float*)d_in[7];
    const float* wxp  = (const float*)d_in[8];
    const float* wdt  = (const float*)d_in[9];
    const float* bdt  = (const float*)d_in[10];
    const float* alog = (const float*)d_in[11];
    const float* Dp   = (const float*)d_in[12];
    const float* wout = (const float*)d_in[13];
    const float* pow_ = (const float*)d_in[14];
    const float* pob  = (const float*)d_in[15];
    float* out = (float*)d_out;

    float* ws = (float*)d_ws;
    float* xi  = ws;                            // NTOK*256 f32 ; later y_bf (u16 NTOK*512)
    float* dty = xi  + (size_t)NTOK * 256;      // NTOK*512 f32 dt ; later ytok_bf
    float* Bm  = dty + (size_t)NTOK * 512;      // NTOK*16 f32
    float* Cm  = Bm  + (size_t)NTOK * 16;       // NTOK*16 f32
    u16* t_bf  = (u16*)(Cm + (size_t)NTOK * 16); // NTOK*256
    u16* xm_bf = t_bf  + (size_t)NTOK * 256;    // NTOK*512
    u16* sz_bf = xm_bf + (size_t)NTOK * 512;    // NTOK*512
    u16* xdb   = sz_bf + (size_t)NTOK * 512;    // NTOK*16
    u16* wb    = xdb   + (size_t)NTOK * 16;     // 548864 u16 weights
    u16* wib  = wb;               // 262144
    u16* wob  = wb + 262144;      // 131072
    u16* piwb = wb + 393216;      // 65536
    u16* powb = wb + 458752;      // 65536
    u16* wxb  = wb + 524288;      // 24576
    u16* y_bf    = (u16*)xi;      // NTOK*512 (xi dead after k1b)
    u16* ytok_bf = (u16*)dty;     // NTOK*256 (dt dead after k4)

    hipLaunchKernelGGL(k0_w2b,  dim3(536), dim3(256), 0, stream, W_in, wout, piw, pow_, wxp, wb);
    hipLaunchKernelGGL(k1a_proj, dim3(NWIN * 4), dim3(256), 0, stream, x, piwb, pib, xi);
    hipLaunchKernelGGL(k1b_ln,  dim3(NTOK / 4), dim3(256), 0, stream, xi, lng, lnb, t_bf);
    hipLaunchKernelGGL(k2_gemm, dim3(144 * 8), dim3(256), 0, stream, t_bf, wib, cw, cb, xm_bf, sz_bf);
    hipLaunchKernelGGL(k3a_xdb, dim3(NTOK / 16), dim3(256), 0, stream, xm_bf, wxb, xdb, Bm, Cm);
    hipLaunchKernelGGL(k3b_dt,  dim3(NTOK / 16), dim3(256), 0, stream, xdb, wdt, bdt, dty);
    hipLaunchKernelGGL(k4_scan, dim3(NWIN), dim3(512), 0, stream, xm_bf, dty, Bm, Cm, sz_bf, alog, Dp, y_bf);
    hipLaunchKernelGGL(k5_gemm, dim3(144 * 2), dim3(256), 0, stream, y_bf, wob, ytok_bf);
    hipLaunchKernelGGL(k6_gemm, dim3(144 * 2), dim3(256), 0, stream, ytok_bf, powb, pob, x, out);
}